// Round 15
// baseline (1694.669 us; speedup 1.0000x reference)
//
#include <hip/hip_runtime.h>

typedef unsigned int u32;
typedef unsigned short u16;
typedef short s16x8 __attribute__((ext_vector_type(8)));
typedef float f32x4 __attribute__((ext_vector_type(4)));

namespace {
constexpr int kB = 16384, kL = 20;

// packed split-bf16 weights in d_ws (u16 elems). per (kt,n): hi[32] | lo[32]
constexpr int OFF_A1 = 0;                       // 128x256
constexpr int OFF_A2 = OFF_A1 + 128 * 256 * 2;  // 256x256
constexpr int OFF_M1 = OFF_A2 + 256 * 256 * 2;  // 128x256
constexpr int OFF_M2 = OFF_M1 + 128 * 256 * 2;  // 256x256
constexpr int OFF_M3 = OFF_M2 + 256 * 256 * 2;  // 256x64
constexpr int OFF_U1 = OFF_M3 + 256 * 64 * 2;   // 64x64
constexpr int OFF_U2 = OFF_U1 + 64 * 64 * 2;    // 128x64
constexpr int OFF_U3 = OFF_U2 + 128 * 64 * 2;   // 64x64
constexpr int PACK_ELEMS = OFF_U3 + 64 * 64 * 2;        // 458752 u16
constexpr size_t MSG_OFF = (size_t)PACK_ELEMS;          // bf16 msgs [b][t][64]
constexpr size_t CD_OFF = MSG_OFF + (size_t)kB * kL * 64;  // f32 carry [b][64]
constexpr size_t WS_NEED = (CD_OFF + (size_t)kB * 64 * 2) * 2;  // ~47 MB

__device__ __forceinline__ u16 f2bf(float x) {
  u32 b = __builtin_bit_cast(u32, x);
  b += 0x7FFFu + ((b >> 16) & 1u);
  return (u16)(b >> 16);
}
__device__ __forceinline__ float bf2f(u16 h) {
  return __builtin_bit_cast(float, (u32)h << 16);
}
__device__ __forceinline__ void split2(float x, u16& hi, u16& lo) {
  hi = f2bf(x);
  lo = f2bf(x - bf2f(hi));
}
__device__ __forceinline__ f32x4 mfma16(s16x8 a, s16x8 b, f32x4 c) {
  return __builtin_amdgcn_mfma_f32_16x16x32_bf16(a, b, c, 0, 0, 0);
}
__device__ __forceinline__ s16x8 ldsf(const u16* p) {
  return *reinterpret_cast<const s16x8*>(p);
}
__device__ __forceinline__ int swz(int row, int idx) { return idx ^ ((row & 7) << 3); }

__device__ __forceinline__ float fast_rcp(float x) {
#if __has_builtin(__builtin_amdgcn_rcpf)
  return __builtin_amdgcn_rcpf(x);
#else
  return 1.0f / x;
#endif
}
__device__ __forceinline__ float tfast(float x) {  // tanh, |err| ~1e-6
#if __has_builtin(__builtin_amdgcn_exp2f)
  float e = __builtin_amdgcn_exp2f(x * 2.8853900817779268f);
#else
  float e = exp2f(x * 2.8853900817779268f);
#endif
  return fmaf(-2.0f, fast_rcp(e + 1.0f), 1.0f);
}
}  // namespace

// epilogue: write 4 acc elems (relu + split) to 256-wide swizzled planes
#define EPI4(A, BB, MB, COL, DH, DL)                                         \
  {                                                                          \
    _Pragma("unroll") for (int i_ = 0; i_ < 4; ++i_) {                       \
      const int row_ = (MB) + g * 4 + i_;                                    \
      u16 h_, l_;                                                            \
      split2(fmaxf((A)[i_] + (BB), 0.f), h_, l_);                            \
      const int o_ = swz(row_, row_ * 256 + (COL));                          \
      (DH)[o_] = h_;                                                         \
      (DL)[o_] = l_;                                                         \
    }                                                                        \
  }

// 256-col layer: rows {MBASE+r15, MBASE+16+r15} x cols {c256, c256+16}
#define TD256(OFFW, BIAS, AH, AL, LDA, DH, DL, MBASE)                        \
  {                                                                          \
    f32x4 a00 = {0.f, 0.f, 0.f, 0.f}, a01 = a00, a10 = a00, a11 = a00;       \
    const u16* Bp_ = wsp + (OFFW);                                           \
    _Pragma("unroll") for (int kt = 0; kt < (LDA) / 32; ++kt) {              \
      const u16* bp0_ = Bp_ + (kt * 256 + c256) * 64 + g * 8;                \
      const u16* bp1_ = Bp_ + (kt * 256 + c256 + 16) * 64 + g * 8;           \
      s16x8 b0h = ldsf(bp0_), b0l = ldsf(bp0_ + 32);                         \
      s16x8 b1h = ldsf(bp1_), b1l = ldsf(bp1_ + 32);                         \
      const int r0_ = (MBASE) + r15, r1_ = (MBASE) + 16 + r15;               \
      const int of0_ = swz(r0_, r0_ * (LDA) + kt * 32 + g * 8);              \
      const int of1_ = swz(r1_, r1_ * (LDA) + kt * 32 + g * 8);              \
      s16x8 a0h = ldsf((AH) + of0_), a0l = ldsf((AL) + of0_);                \
      s16x8 a1h = ldsf((AH) + of1_), a1l = ldsf((AL) + of1_);                \
      a00 = mfma16(a0h, b0h, a00);                                           \
      a00 = mfma16(a0l, b0h, a00);                                           \
      a00 = mfma16(a0h, b0l, a00);                                           \
      a01 = mfma16(a0h, b1h, a01);                                           \
      a01 = mfma16(a0l, b1h, a01);                                           \
      a01 = mfma16(a0h, b1l, a01);                                           \
      a10 = mfma16(a1h, b0h, a10);                                           \
      a10 = mfma16(a1l, b0h, a10);                                           \
      a10 = mfma16(a1h, b0l, a10);                                           \
      a11 = mfma16(a1h, b1h, a11);                                           \
      a11 = mfma16(a1l, b1h, a11);                                           \
      a11 = mfma16(a1h, b1l, a11);                                           \
    }                                                                        \
    const float bb0_ = (BIAS)[c256], bb1_ = (BIAS)[c256 + 16];               \
    EPI4(a00, bb0_, (MBASE), c256, DH, DL);                                  \
    EPI4(a01, bb1_, (MBASE), c256 + 16, DH, DL);                             \
    EPI4(a10, bb0_, (MBASE) + 16, c256, DH, DL);                             \
    EPI4(a11, bb1_, (MBASE) + 16, c256 + 16, DH, DL);                        \
  }

// 64-col layer: row ROWQ*16+r15, col c64, K = KK, A stride LDA -> acc64
#define MM64(OFFW, KK, AH, AL, LDA, ROWQ)                                    \
  f32x4 acc64 = {0.f, 0.f, 0.f, 0.f};                                        \
  {                                                                          \
    const u16* Bp_ = wsp + (OFFW);                                           \
    _Pragma("unroll") for (int kt = 0; kt < (KK) / 32; ++kt) {               \
      const u16* bp_ = Bp_ + (kt * 64 + c64) * 64 + g * 8;                   \
      s16x8 bh = ldsf(bp_), bl = ldsf(bp_ + 32);                             \
      const int ra_ = (ROWQ) * 16 + r15;                                     \
      const int ofa_ = swz(ra_, ra_ * (LDA) + kt * 32 + g * 8);              \
      s16x8 ah = ldsf((AH) + ofa_), al = ldsf((AL) + ofa_);                  \
      acc64 = mfma16(ah, bh, acc64);                                         \
      acc64 = mfma16(al, bh, acc64);                                         \
      acc64 = mfma16(ah, bl, acc64);                                         \
    }                                                                        \
  }

// ---------------- prep: pack weights into split-bf16 frag layout ----------------
__global__ __launch_bounds__(256) void prep_kernel(
    const float* __restrict__ aW1, const float* __restrict__ aW2,
    const float* __restrict__ mW1, const float* __restrict__ mW2,
    const float* __restrict__ mW3, const float* __restrict__ uW1,
    const float* __restrict__ uW2, const float* __restrict__ uW3,
    u16* __restrict__ ws) {
  const float* Ws[8] = {aW1, aW2, mW1, mW2, mW3, uW1, uW2, uW3};
  const int Ns[8]  = {256, 256, 256, 256, 64, 64, 64, 64};
  const int dst[8] = {OFF_A1, OFF_A2, OFF_M1, OFF_M2, OFF_M3, OFF_U1, OFF_U2, OFF_U3};
  const int cnt[8] = {32768, 65536, 32768, 65536, 16384, 4096, 8192, 4096};
  const int total = 229376;
  for (int e = blockIdx.x * 256 + threadIdx.x; e < total; e += gridDim.x * 256) {
    int l = 0, base = 0;
    while (e - base >= cnt[l]) { base += cnt[l]; ++l; }
    const int s = e - base, N = Ns[l];
    const int k = s / N, n = s % N;
    u16 hi, lo;
    split2(Ws[l][s], hi, lo);
    const int ob = dst[l] + ((k >> 5) * N + n) * 64 + (k & 31);
    ws[ob] = hi;
    ws[ob + 32] = lo;
  }
}

// ---------------- BU step t: msg_t = f(state_t, msg_{t+1}) ----------------
__global__ __launch_bounds__(512) void bu_step_kernel(
    const float* __restrict__ state,
    const float* __restrict__ ub1, const float* __restrict__ ub2,
    const float* __restrict__ ub3,
    const u16* __restrict__ wsp, u16* __restrict__ msgs,
    float* __restrict__ carry, int t) {
  __shared__ __align__(16) u16 lds[20480];  // 40 KB
  u16* XSH = lds;                // 32x64
  u16* XSL = lds + 2048;
  u16* XMH = lds + 4096;         // 32x128
  u16* XML = lds + 8192;
  u16* H2H = lds + 12288;        // 32x64
  u16* H2L = lds + 14336;
  float* SMC = reinterpret_cast<float*>(lds + 16384);  // 32x64 f32

  const int tid = threadIdx.x;
  const int wv = tid >> 6, lane = tid & 63;
  const int r15 = lane & 15, g = lane >> 4;
  const int nq = wv & 3;
  const int rowq = wv >> 2;      // 0..1 (rows rowq*16)
  const int nr = tid >> 4, np = tid & 15;
  const int rowBase = blockIdx.x * 32;
  const int c64 = nq * 16 + r15;
  const float ub1v = ub1[c64], ub2v = ub2[c64], ub3v = ub3[c64];

  {  // s0: stage state(t) -> XS ; XM[64:] = split(tanh(m_prev))
    f32x4 v = *reinterpret_cast<const f32x4*>(
        state + ((size_t)(rowBase + nr) * kL + t) * 64 + np * 4);
    u16 h0, h1, h2, h3, l0, l1, l2, l3;
    split2(v[0], h0, l0); split2(v[1], h1, l1);
    split2(v[2], h2, l2); split2(v[3], h3, l3);
    const int o = swz(nr, nr * 64 + np * 4);
    *(u32*)&XSH[o] = (u32)h0 | ((u32)h1 << 16);
    *(u32*)&XSH[o + 2] = (u32)h2 | ((u32)h3 << 16);
    *(u32*)&XSL[o] = (u32)l0 | ((u32)l1 << 16);
    *(u32*)&XSL[o + 2] = (u32)l2 | ((u32)l3 << 16);

    f32x4 mp = {0.f, 0.f, 0.f, 0.f};
    if (t < kL - 1)
      mp = *reinterpret_cast<const f32x4*>(carry + (size_t)(rowBase + nr) * 64 + np * 4);
    u16 mh0, mh1, mh2, mh3, ml0, ml1, ml2, ml3;
    split2(tfast(mp[0]), mh0, ml0); split2(tfast(mp[1]), mh1, ml1);
    split2(tfast(mp[2]), mh2, ml2); split2(tfast(mp[3]), mh3, ml3);
    const int om = swz(nr, nr * 128 + 64 + np * 4);
    *(u32*)&XMH[om] = (u32)mh0 | ((u32)mh1 << 16);
    *(u32*)&XMH[om + 2] = (u32)mh2 | ((u32)mh3 << 16);
    *(u32*)&XML[om] = (u32)ml0 | ((u32)ml1 << 16);
    *(u32*)&XML[om + 2] = (u32)ml2 | ((u32)ml3 << 16);
  }
  __syncthreads();
  {  // s1: U1 -> SMC raw
    MM64(OFF_U1, 64, XSH, XSL, 64, rowq);
    #pragma unroll
    for (int i = 0; i < 4; ++i)
      SMC[(rowq * 16 + g * 4 + i) * 64 + c64] = acc64[i] + ub1v;
  }
  __syncthreads();
  {  // s2: normalize + tanh -> XM[0:64]
    f32x4 v = *reinterpret_cast<const f32x4*>(SMC + nr * 64 + np * 4);
    float ss = v[0]*v[0] + v[1]*v[1] + v[2]*v[2] + v[3]*v[3];
    ss += __shfl_xor(ss, 8); ss += __shfl_xor(ss, 4);
    ss += __shfl_xor(ss, 2); ss += __shfl_xor(ss, 1);
    const float inv = 1.f / fmaxf(sqrtf(ss), 1e-12f);
    u16 h0, h1, h2, h3, l0, l1, l2, l3;
    split2(tfast(v[0] * inv), h0, l0); split2(tfast(v[1] * inv), h1, l1);
    split2(tfast(v[2] * inv), h2, l2); split2(tfast(v[3] * inv), h3, l3);
    const int o = swz(nr, nr * 128 + np * 4);
    *(u32*)&XMH[o] = (u32)h0 | ((u32)h1 << 16);
    *(u32*)&XMH[o + 2] = (u32)h2 | ((u32)h3 << 16);
    *(u32*)&XML[o] = (u32)l0 | ((u32)l1 << 16);
    *(u32*)&XML[o + 2] = (u32)l2 | ((u32)l3 << 16);
  }
  __syncthreads();
  {  // s3: U2 (K=128) -> tanh -> H2
    MM64(OFF_U2, 128, XMH, XML, 128, rowq);
    #pragma unroll
    for (int i = 0; i < 4; ++i) {
      u16 hh, ll;
      split2(tfast(acc64[i] + ub2v), hh, ll);
      const int row = rowq * 16 + g * 4 + i;
      const int o = swz(row, row * 64 + c64);
      H2H[o] = hh; H2L[o] = ll;
    }
  }
  __syncthreads();
  {  // s4: U3 -> SMC raw
    MM64(OFF_U3, 64, H2H, H2L, 64, rowq);
    #pragma unroll
    for (int i = 0; i < 4; ++i)
      SMC[(rowq * 16 + g * 4 + i) * 64 + c64] = acc64[i] + ub3v;
  }
  __syncthreads();
  {  // s5: normalize -> msg: store bf16 msgs[b][t] + f32 carry
    f32x4 v = *reinterpret_cast<const f32x4*>(SMC + nr * 64 + np * 4);
    float ss = v[0]*v[0] + v[1]*v[1] + v[2]*v[2] + v[3]*v[3];
    ss += __shfl_xor(ss, 8); ss += __shfl_xor(ss, 4);
    ss += __shfl_xor(ss, 2); ss += __shfl_xor(ss, 1);
    const float inv = 1.f / fmaxf(sqrtf(ss), 1e-12f);
    f32x4 m;
    m[0] = v[0] * inv; m[1] = v[1] * inv; m[2] = v[2] * inv; m[3] = v[3] * inv;
    u16* mp = msgs + ((size_t)(rowBase + nr) * kL + t) * 64 + np * 4;
    *(u32*)mp = (u32)f2bf(m[0]) | ((u32)f2bf(m[1]) << 16);
    *(u32*)(mp + 2) = (u32)f2bf(m[2]) | ((u32)f2bf(m[3]) << 16);
    *reinterpret_cast<f32x4*>(carry + (size_t)(rowBase + nr) * 64 + np * 4) = m;
  }
}

// -------- TD step t: RPB=64, 1024 threads (16 waves = 8 colg x 2 rowg) --------
__global__ __launch_bounds__(1024) void td_step_kernel(
    const float* __restrict__ ab1, const float* __restrict__ ab2,
    const float* __restrict__ aW3, const float* __restrict__ ab3,
    const float* __restrict__ mb1, const float* __restrict__ mb2,
    const float* __restrict__ mb3,
    const u16* __restrict__ wsp, const u16* __restrict__ msgs,
    float* __restrict__ carry, float* __restrict__ out, int t) {
  __shared__ __align__(16) u16 lds[81920];  // 160 KB
  u16* XMH = lds;             // 64x128  (16 KB)
  u16* XML = lds + 8192;
  u16* B1H = lds + 16384;     // 64x256  (32 KB)
  u16* B1L = lds + 32768;
  u16* B2H = lds + 49152;     // 64x256
  u16* B2L = lds + 65536;
  float* SMC = reinterpret_cast<float*>(B1H);  // 64x64 f32 (16 KB), B1 dead after M2

  const int tid = threadIdx.x;
  const int wv = tid >> 6, lane = tid & 63;
  const int r15 = lane & 15, g = lane >> 4;
  const int colg = wv & 7, rowg = wv >> 3;   // 256-col layers
  const int nq = wv & 3, rowq = wv >> 2;     // 64-col layer (M3): 4 colx4 row tiles
  const int nr = tid >> 4, np = tid & 15;    // 64 rows x 16 lanes
  const int rowBase = blockIdx.x * 64;
  const int c256 = colg * 32 + r15;
  const int mbase = rowg * 32;
  const int c64 = nq * 16 + r15;
  const float mb3v = mb3[c64];
  const float ab3v = ab3[0];
  const f32x4 w3a = *reinterpret_cast<const f32x4*>(aW3 + np * 16);
  const f32x4 w3b = *reinterpret_cast<const f32x4*>(aW3 + np * 16 + 4);
  const f32x4 w3c = *reinterpret_cast<const f32x4*>(aW3 + np * 16 + 8);
  const f32x4 w3d = *reinterpret_cast<const f32x4*>(aW3 + np * 16 + 12);

  {  // p0: XM = [split(tanh(msg_t)) | split(tanh(m_{t-1}))]
    const u16* mp = msgs + ((size_t)(rowBase + nr) * kL + t) * 64 + np * 4;
    const u32 w0 = *(const u32*)mp;
    const u32 w1 = *(const u32*)(mp + 2);
    u16 h0, h1, h2, h3, l0, l1, l2, l3;
    split2(tfast(bf2f((u16)w0)), h0, l0);
    split2(tfast(bf2f((u16)(w0 >> 16))), h1, l1);
    split2(tfast(bf2f((u16)w1)), h2, l2);
    split2(tfast(bf2f((u16)(w1 >> 16))), h3, l3);
    const int o = swz(nr, nr * 128 + np * 4);
    *(u32*)&XMH[o] = (u32)h0 | ((u32)h1 << 16);
    *(u32*)&XMH[o + 2] = (u32)h2 | ((u32)h3 << 16);
    *(u32*)&XML[o] = (u32)l0 | ((u32)l1 << 16);
    *(u32*)&XML[o + 2] = (u32)l2 | ((u32)l3 << 16);

    f32x4 mprev = {0.f, 0.f, 0.f, 0.f};
    if (t > 0)
      mprev = *reinterpret_cast<const f32x4*>(carry + (size_t)(rowBase + nr) * 64 + np * 4);
    u16 mh0, mh1, mh2, mh3, ml0, ml1, ml2, ml3;
    split2(tfast(mprev[0]), mh0, ml0); split2(tfast(mprev[1]), mh1, ml1);
    split2(tfast(mprev[2]), mh2, ml2); split2(tfast(mprev[3]), mh3, ml3);
    const int om = swz(nr, nr * 128 + 64 + np * 4);
    *(u32*)&XMH[om] = (u32)mh0 | ((u32)mh1 << 16);
    *(u32*)&XMH[om + 2] = (u32)mh2 | ((u32)mh3 << 16);
    *(u32*)&XML[om] = (u32)ml0 | ((u32)ml1 << 16);
    *(u32*)&XML[om + 2] = (u32)ml2 | ((u32)ml3 << 16);
  }
  __syncthreads();
  {  // p1: A1 -> B1
    TD256(OFF_A1, ab1, XMH, XML, 128, B1H, B1L, mbase);
  }
  __syncthreads();
  {  // p2: A2 -> B2
    TD256(OFF_A2, ab2, B1H, B1L, 256, B2H, B2L, mbase);
  }
  __syncthreads();
  {  // p3: a3 (B2 -> out) + M1 (XM -> B1)
    {
      const int o0 = swz(nr, nr * 256 + np * 16);
      const int o1 = swz(nr, nr * 256 + np * 16 + 8);
      s16x8 d0h = ldsf(B2H + o0), d1h = ldsf(B2H + o1);
      s16x8 d0l = ldsf(B2L + o0), d1l = ldsf(B2L + o1);
      float sum = 0.f;
      #pragma unroll
      for (int j = 0; j < 4; ++j) {
        sum += (bf2f((u16)d0h[j]) + bf2f((u16)d0l[j])) * w3a[j];
        sum += (bf2f((u16)d0h[4 + j]) + bf2f((u16)d0l[4 + j])) * w3b[j];
        sum += (bf2f((u16)d1h[j]) + bf2f((u16)d1l[j])) * w3c[j];
        sum += (bf2f((u16)d1h[4 + j]) + bf2f((u16)d1l[4 + j])) * w3d[j];
      }
      sum += __shfl_xor(sum, 8); sum += __shfl_xor(sum, 4);
      sum += __shfl_xor(sum, 2); sum += __shfl_xor(sum, 1);
      if (np == 0) out[(size_t)(rowBase + nr) * kL + t] = tfast(sum + ab3v);
    }
    TD256(OFF_M1, mb1, XMH, XML, 128, B1H, B1L, mbase);
  }
  __syncthreads();
  {  // p4: M2 -> B2
    TD256(OFF_M2, mb2, B1H, B1L, 256, B2H, B2L, mbase);
  }
  __syncthreads();
  {  // p5: M3 -> SMC raw (aliases B1H; B1 dead)
    MM64(OFF_M3, 256, B2H, B2L, 256, rowq);
    #pragma unroll
    for (int i = 0; i < 4; ++i)
      SMC[(rowq * 16 + g * 4 + i) * 64 + c64] = acc64[i] + mb3v;
  }
  __syncthreads();
  {  // p6: normalize -> m_t -> carry
    f32x4 v = *reinterpret_cast<const f32x4*>(SMC + nr * 64 + np * 4);
    float ss = v[0]*v[0] + v[1]*v[1] + v[2]*v[2] + v[3]*v[3];
    ss += __shfl_xor(ss, 8); ss += __shfl_xor(ss, 4);
    ss += __shfl_xor(ss, 2); ss += __shfl_xor(ss, 1);
    const float inv = 1.f / fmaxf(sqrtf(ss), 1e-12f);
    f32x4 m;
    m[0] = v[0] * inv; m[1] = v[1] * inv; m[2] = v[2] * inv; m[3] = v[3] * inv;
    *reinterpret_cast<f32x4*>(carry + (size_t)(rowBase + nr) * 64 + np * 4) = m;
  }
}

extern "C" void kernel_launch(void* const* d_in, const int* in_sizes, int n_in,
                              void* d_out, int out_size, void* d_ws, size_t ws_size,
                              hipStream_t stream) {
  (void)in_sizes; (void)n_in; (void)out_size;
  const float* state = (const float*)d_in[0];
  const float* uW1 = (const float*)d_in[1];
  const float* ub1 = (const float*)d_in[2];
  const float* uW2 = (const float*)d_in[3];
  const float* ub2 = (const float*)d_in[4];
  const float* uW3 = (const float*)d_in[5];
  const float* ub3 = (const float*)d_in[6];
  const float* aW1 = (const float*)d_in[7];
  const float* ab1 = (const float*)d_in[8];
  const float* aW2 = (const float*)d_in[9];
  const float* ab2 = (const float*)d_in[10];
  const float* aW3 = (const float*)d_in[11];
  const float* ab3 = (const float*)d_in[12];
  const float* mW1 = (const float*)d_in[13];
  const float* mb1 = (const float*)d_in[14];
  const float* mW2 = (const float*)d_in[15];
  const float* mb2 = (const float*)d_in[16];
  const float* mW3 = (const float*)d_in[17];
  const float* mb3 = (const float*)d_in[18];
  u16* wsp = (u16*)d_ws;
  float* out = (float*)d_out;

  if (ws_size < WS_NEED) return;
  u16* msgs = wsp + MSG_OFF;
  float* carry = reinterpret_cast<float*>(wsp + CD_OFF);

  hipLaunchKernelGGL(prep_kernel, dim3(896), dim3(256), 0, stream,
                     aW1, aW2, mW1, mW2, mW3, uW1, uW2, uW3, wsp);
  for (int t = kL - 1; t >= 0; --t)
    hipLaunchKernelGGL(bu_step_kernel, dim3(kB / 32), dim3(512), 0, stream,
                       state, ub1, ub2, ub3, wsp, msgs, carry, t);
  for (int t = 0; t < kL; ++t)
    hipLaunchKernelGGL(td_step_kernel, dim3(kB / 64), dim3(1024), 0, stream,
                       ab1, ab2, aW3, ab3, mb1, mb2, mb3,
                       wsp, msgs, carry, out, t);
}

// Round 16
// 1225.805 us; speedup vs baseline: 1.3825x; 1.3825x over previous
//
#include <hip/hip_runtime.h>

typedef unsigned int u32;
typedef unsigned short u16;
typedef short s16x8 __attribute__((ext_vector_type(8)));
typedef float f32x4 __attribute__((ext_vector_type(4)));

namespace {
constexpr int kB = 16384, kL = 20;

// packed split-bf16 weights in d_ws (u16 elems). per (kt,n): hi[32] | lo[32]
constexpr int OFF_A1 = 0;                       // 128x256
constexpr int OFF_A2 = OFF_A1 + 128 * 256 * 2;  // 256x256
constexpr int OFF_M1 = OFF_A2 + 256 * 256 * 2;  // 128x256
constexpr int OFF_M2 = OFF_M1 + 128 * 256 * 2;  // 256x256
constexpr int OFF_M3 = OFF_M2 + 256 * 256 * 2;  // 256x64
constexpr int OFF_U1 = OFF_M3 + 256 * 64 * 2;   // 64x64
constexpr int OFF_U2 = OFF_U1 + 64 * 64 * 2;    // 128x64
constexpr int OFF_U3 = OFF_U2 + 128 * 64 * 2;   // 64x64
constexpr int PACK_ELEMS = OFF_U3 + 64 * 64 * 2;        // 458752 u16
constexpr size_t MSG_OFF = (size_t)PACK_ELEMS;          // bf16 msgs [b][t][64]
constexpr size_t CD_OFF = MSG_OFF + (size_t)kB * kL * 64;  // f32 carry [b][64]
constexpr size_t WS_NEED = (CD_OFF + (size_t)kB * 64 * 2) * 2;  // ~47 MB

__device__ __forceinline__ u16 f2bf(float x) {
  u32 b = __builtin_bit_cast(u32, x);
  b += 0x7FFFu + ((b >> 16) & 1u);
  return (u16)(b >> 16);
}
__device__ __forceinline__ float bf2f(u16 h) {
  return __builtin_bit_cast(float, (u32)h << 16);
}
__device__ __forceinline__ void split2(float x, u16& hi, u16& lo) {
  hi = f2bf(x);
  lo = f2bf(x - bf2f(hi));
}
__device__ __forceinline__ f32x4 mfma16(s16x8 a, s16x8 b, f32x4 c) {
  return __builtin_amdgcn_mfma_f32_16x16x32_bf16(a, b, c, 0, 0, 0);
}
__device__ __forceinline__ s16x8 ldsf(const u16* p) {
  return *reinterpret_cast<const s16x8*>(p);
}
__device__ __forceinline__ int swz(int row, int idx) { return idx ^ ((row & 7) << 3); }

__device__ __forceinline__ float fast_rcp(float x) {
#if __has_builtin(__builtin_amdgcn_rcpf)
  return __builtin_amdgcn_rcpf(x);
#else
  return 1.0f / x;
#endif
}
__device__ __forceinline__ float tfast(float x) {  // tanh, |err| ~1e-6
#if __has_builtin(__builtin_amdgcn_exp2f)
  float e = __builtin_amdgcn_exp2f(x * 2.8853900817779268f);
#else
  float e = exp2f(x * 2.8853900817779268f);
#endif
  return fmaf(-2.0f, fast_rcp(e + 1.0f), 1.0f);
}
}  // namespace

// epilogue: write 4 acc elems (relu + split) to 256-wide swizzled planes
#define EPI4(A, BB, MB, COL, DH, DL)                                         \
  {                                                                          \
    _Pragma("unroll") for (int i_ = 0; i_ < 4; ++i_) {                       \
      const int row_ = (MB) + g * 4 + i_;                                    \
      u16 h_, l_;                                                            \
      split2(fmaxf((A)[i_] + (BB), 0.f), h_, l_);                            \
      const int o_ = swz(row_, row_ * 256 + (COL));                          \
      (DH)[o_] = h_;                                                         \
      (DL)[o_] = l_;                                                         \
    }                                                                        \
  }

// one m-tile's A-reads + 6 MFMAs against current B regs (b0h/b0l/b1h/b1l)
#define KTM(M, C0, C1, AH, AL, LDA, KT)                                      \
  {                                                                          \
    const int rm_ = (M) * 16 + r15;                                          \
    const int of_ = swz(rm_, rm_ * (LDA) + (KT) * 32 + g * 8);               \
    s16x8 amh = ldsf((AH) + of_), aml = ldsf((AL) + of_);                    \
    C0 = mfma16(amh, b0h, C0);                                               \
    C0 = mfma16(aml, b0h, C0);                                               \
    C0 = mfma16(amh, b0l, C0);                                               \
    C1 = mfma16(amh, b1h, C1);                                               \
    C1 = mfma16(aml, b1h, C1);                                               \
    C1 = mfma16(amh, b1l, C1);                                               \
  }

// 256-col layer, RPB=64: wave owns cols {c256, c256+16} x ALL 64 rows (NM=4)
#define TD256x4(OFFW, BIAS, AH, AL, LDA, DH, DL)                             \
  {                                                                          \
    f32x4 c00 = {0.f, 0.f, 0.f, 0.f}, c01 = c00, c10 = c00, c11 = c00;       \
    f32x4 c20 = c00, c21 = c00, c30 = c00, c31 = c00;                        \
    const u16* Bp_ = wsp + (OFFW);                                           \
    _Pragma("unroll") for (int kt = 0; kt < (LDA) / 32; ++kt) {              \
      const u16* bp0_ = Bp_ + (kt * 256 + c256) * 64 + g * 8;                \
      const u16* bp1_ = Bp_ + (kt * 256 + c256 + 16) * 64 + g * 8;           \
      s16x8 b0h = ldsf(bp0_), b0l = ldsf(bp0_ + 32);                         \
      s16x8 b1h = ldsf(bp1_), b1l = ldsf(bp1_ + 32);                         \
      KTM(0, c00, c01, AH, AL, LDA, kt);                                     \
      KTM(1, c10, c11, AH, AL, LDA, kt);                                     \
      KTM(2, c20, c21, AH, AL, LDA, kt);                                     \
      KTM(3, c30, c31, AH, AL, LDA, kt);                                     \
    }                                                                        \
    const float bb0_ = (BIAS)[c256], bb1_ = (BIAS)[c256 + 16];               \
    EPI4(c00, bb0_, 0, c256, DH, DL);                                        \
    EPI4(c01, bb1_, 0, c256 + 16, DH, DL);                                   \
    EPI4(c10, bb0_, 16, c256, DH, DL);                                       \
    EPI4(c11, bb1_, 16, c256 + 16, DH, DL);                                  \
    EPI4(c20, bb0_, 32, c256, DH, DL);                                       \
    EPI4(c21, bb1_, 32, c256 + 16, DH, DL);                                  \
    EPI4(c30, bb0_, 48, c256, DH, DL);                                       \
    EPI4(c31, bb1_, 48, c256 + 16, DH, DL);                                  \
  }

// 64-col layer for BU (RPB=32): row ROWQ*16+r15, col c64, K=KK
#define MM64(OFFW, KK, AH, AL, LDA, ROWQ)                                    \
  f32x4 acc64 = {0.f, 0.f, 0.f, 0.f};                                        \
  {                                                                          \
    const u16* Bp_ = wsp + (OFFW);                                           \
    _Pragma("unroll") for (int kt = 0; kt < (KK) / 32; ++kt) {               \
      const u16* bp_ = Bp_ + (kt * 64 + c64) * 64 + g * 8;                   \
      s16x8 bh = ldsf(bp_), bl = ldsf(bp_ + 32);                             \
      const int ra_ = (ROWQ) * 16 + r15;                                     \
      const int ofa_ = swz(ra_, ra_ * (LDA) + kt * 32 + g * 8);              \
      s16x8 ah = ldsf((AH) + ofa_), al = ldsf((AL) + ofa_);                  \
      acc64 = mfma16(ah, bh, acc64);                                         \
      acc64 = mfma16(al, bh, acc64);                                         \
      acc64 = mfma16(ah, bl, acc64);                                         \
    }                                                                        \
  }

// ---------------- prep: pack weights into split-bf16 frag layout ----------------
__global__ __launch_bounds__(256) void prep_kernel(
    const float* __restrict__ aW1, const float* __restrict__ aW2,
    const float* __restrict__ mW1, const float* __restrict__ mW2,
    const float* __restrict__ mW3, const float* __restrict__ uW1,
    const float* __restrict__ uW2, const float* __restrict__ uW3,
    u16* __restrict__ ws) {
  const float* Ws[8] = {aW1, aW2, mW1, mW2, mW3, uW1, uW2, uW3};
  const int Ns[8]  = {256, 256, 256, 256, 64, 64, 64, 64};
  const int dst[8] = {OFF_A1, OFF_A2, OFF_M1, OFF_M2, OFF_M3, OFF_U1, OFF_U2, OFF_U3};
  const int cnt[8] = {32768, 65536, 32768, 65536, 16384, 4096, 8192, 4096};
  const int total = 229376;
  for (int e = blockIdx.x * 256 + threadIdx.x; e < total; e += gridDim.x * 256) {
    int l = 0, base = 0;
    while (e - base >= cnt[l]) { base += cnt[l]; ++l; }
    const int s = e - base, N = Ns[l];
    const int k = s / N, n = s % N;
    u16 hi, lo;
    split2(Ws[l][s], hi, lo);
    const int ob = dst[l] + ((k >> 5) * N + n) * 64 + (k & 31);
    ws[ob] = hi;
    ws[ob + 32] = lo;
  }
}

// ---------------- BU step t (RPB=32, 512 thr, clean at 5.4 us) ----------------
__global__ __launch_bounds__(512) void bu_step_kernel(
    const float* __restrict__ state,
    const float* __restrict__ ub1, const float* __restrict__ ub2,
    const float* __restrict__ ub3,
    const u16* __restrict__ wsp, u16* __restrict__ msgs,
    float* __restrict__ carry, int t) {
  __shared__ __align__(16) u16 lds[20480];  // 40 KB
  u16* XSH = lds;                // 32x64
  u16* XSL = lds + 2048;
  u16* XMH = lds + 4096;         // 32x128
  u16* XML = lds + 8192;
  u16* H2H = lds + 12288;        // 32x64
  u16* H2L = lds + 14336;
  float* SMC = reinterpret_cast<float*>(lds + 16384);  // 32x64 f32

  const int tid = threadIdx.x;
  const int wv = tid >> 6, lane = tid & 63;
  const int r15 = lane & 15, g = lane >> 4;
  const int nq = wv & 3;
  const int rowq = wv >> 2;
  const int nr = tid >> 4, np = tid & 15;
  const int rowBase = blockIdx.x * 32;
  const int c64 = nq * 16 + r15;
  const float ub1v = ub1[c64], ub2v = ub2[c64], ub3v = ub3[c64];

  {  // s0: stage state(t) -> XS ; XM[64:] = split(tanh(m_prev))
    f32x4 v = *reinterpret_cast<const f32x4*>(
        state + ((size_t)(rowBase + nr) * kL + t) * 64 + np * 4);
    u16 h0, h1, h2, h3, l0, l1, l2, l3;
    split2(v[0], h0, l0); split2(v[1], h1, l1);
    split2(v[2], h2, l2); split2(v[3], h3, l3);
    const int o = swz(nr, nr * 64 + np * 4);
    *(u32*)&XSH[o] = (u32)h0 | ((u32)h1 << 16);
    *(u32*)&XSH[o + 2] = (u32)h2 | ((u32)h3 << 16);
    *(u32*)&XSL[o] = (u32)l0 | ((u32)l1 << 16);
    *(u32*)&XSL[o + 2] = (u32)l2 | ((u32)l3 << 16);

    f32x4 mp = {0.f, 0.f, 0.f, 0.f};
    if (t < kL - 1)
      mp = *reinterpret_cast<const f32x4*>(carry + (size_t)(rowBase + nr) * 64 + np * 4);
    u16 mh0, mh1, mh2, mh3, ml0, ml1, ml2, ml3;
    split2(tfast(mp[0]), mh0, ml0); split2(tfast(mp[1]), mh1, ml1);
    split2(tfast(mp[2]), mh2, ml2); split2(tfast(mp[3]), mh3, ml3);
    const int om = swz(nr, nr * 128 + 64 + np * 4);
    *(u32*)&XMH[om] = (u32)mh0 | ((u32)mh1 << 16);
    *(u32*)&XMH[om + 2] = (u32)mh2 | ((u32)mh3 << 16);
    *(u32*)&XML[om] = (u32)ml0 | ((u32)ml1 << 16);
    *(u32*)&XML[om + 2] = (u32)ml2 | ((u32)ml3 << 16);
  }
  __syncthreads();
  {  // s1: U1 -> SMC raw
    MM64(OFF_U1, 64, XSH, XSL, 64, rowq);
    #pragma unroll
    for (int i = 0; i < 4; ++i)
      SMC[(rowq * 16 + g * 4 + i) * 64 + c64] = acc64[i] + ub1v;
  }
  __syncthreads();
  {  // s2: normalize + tanh -> XM[0:64]
    f32x4 v = *reinterpret_cast<const f32x4*>(SMC + nr * 64 + np * 4);
    float ss = v[0]*v[0] + v[1]*v[1] + v[2]*v[2] + v[3]*v[3];
    ss += __shfl_xor(ss, 8); ss += __shfl_xor(ss, 4);
    ss += __shfl_xor(ss, 2); ss += __shfl_xor(ss, 1);
    const float inv = 1.f / fmaxf(sqrtf(ss), 1e-12f);
    u16 h0, h1, h2, h3, l0, l1, l2, l3;
    split2(tfast(v[0] * inv), h0, l0); split2(tfast(v[1] * inv), h1, l1);
    split2(tfast(v[2] * inv), h2, l2); split2(tfast(v[3] * inv), h3, l3);
    const int o = swz(nr, nr * 128 + np * 4);
    *(u32*)&XMH[o] = (u32)h0 | ((u32)h1 << 16);
    *(u32*)&XMH[o + 2] = (u32)h2 | ((u32)h3 << 16);
    *(u32*)&XML[o] = (u32)l0 | ((u32)l1 << 16);
    *(u32*)&XML[o + 2] = (u32)l2 | ((u32)l3 << 16);
  }
  __syncthreads();
  {  // s3: U2 (K=128) -> tanh -> H2
    MM64(OFF_U2, 128, XMH, XML, 128, rowq);
    #pragma unroll
    for (int i = 0; i < 4; ++i) {
      u16 hh, ll;
      split2(tfast(acc64[i] + ub2v), hh, ll);
      const int row = rowq * 16 + g * 4 + i;
      const int o = swz(row, row * 64 + c64);
      H2H[o] = hh; H2L[o] = ll;
    }
  }
  __syncthreads();
  {  // s4: U3 -> SMC raw
    MM64(OFF_U3, 64, H2H, H2L, 64, rowq);
    #pragma unroll
    for (int i = 0; i < 4; ++i)
      SMC[(rowq * 16 + g * 4 + i) * 64 + c64] = acc64[i] + ub3v;
  }
  __syncthreads();
  {  // s5: normalize -> msg: store bf16 msgs[b][t] + f32 carry
    f32x4 v = *reinterpret_cast<const f32x4*>(SMC + nr * 64 + np * 4);
    float ss = v[0]*v[0] + v[1]*v[1] + v[2]*v[2] + v[3]*v[3];
    ss += __shfl_xor(ss, 8); ss += __shfl_xor(ss, 4);
    ss += __shfl_xor(ss, 2); ss += __shfl_xor(ss, 1);
    const float inv = 1.f / fmaxf(sqrtf(ss), 1e-12f);
    f32x4 m;
    m[0] = v[0] * inv; m[1] = v[1] * inv; m[2] = v[2] * inv; m[3] = v[3] * inv;
    u16* mp = msgs + ((size_t)(rowBase + nr) * kL + t) * 64 + np * 4;
    *(u32*)mp = (u32)f2bf(m[0]) | ((u32)f2bf(m[1]) << 16);
    *(u32*)(mp + 2) = (u32)f2bf(m[2]) | ((u32)f2bf(m[3]) << 16);
    *reinterpret_cast<f32x4*>(carry + (size_t)(rowBase + nr) * 64 + np * 4) = m;
  }
}

// -------- TD step t: RPB=64 at 512 threads (8 waves, NM=4, NT=2) --------
__global__ __launch_bounds__(512) void td_step_kernel(
    const float* __restrict__ ab1, const float* __restrict__ ab2,
    const float* __restrict__ aW3, const float* __restrict__ ab3,
    const float* __restrict__ mb1, const float* __restrict__ mb2,
    const float* __restrict__ mb3,
    const u16* __restrict__ wsp, const u16* __restrict__ msgs,
    float* __restrict__ carry, float* __restrict__ out, int t) {
  __shared__ __align__(16) u16 lds[81920];  // 160 KB
  u16* XMH = lds;             // 64x128
  u16* XML = lds + 8192;
  u16* B1H = lds + 16384;     // 64x256
  u16* B1L = lds + 32768;
  u16* B2H = lds + 49152;     // 64x256
  u16* B2L = lds + 65536;
  float* SMC = reinterpret_cast<float*>(B1H);  // 64x64 f32 (16 KB), B1 dead after M2

  const int tid = threadIdx.x;
  const int wv = tid >> 6, lane = tid & 63;
  const int r15 = lane & 15, g = lane >> 4;
  const int nq = wv & 3, rowh = wv >> 2;     // M3: 4 col-tiles x 2 row-halves
  const int nr = tid >> 4, np = tid & 15;    // 32 rows x 16 lanes (x2 row passes)
  const int rowBase = blockIdx.x * 64;
  const int c256 = wv * 32 + r15;            // wave owns 32 cols
  const int c64 = nq * 16 + r15;
  const float mb3v = mb3[c64];
  const float ab3v = ab3[0];
  const f32x4 w3a = *reinterpret_cast<const f32x4*>(aW3 + np * 16);
  const f32x4 w3b = *reinterpret_cast<const f32x4*>(aW3 + np * 16 + 4);
  const f32x4 w3c = *reinterpret_cast<const f32x4*>(aW3 + np * 16 + 8);
  const f32x4 w3d = *reinterpret_cast<const f32x4*>(aW3 + np * 16 + 12);

  {  // p0: XM rows {nr, nr+32} = [split(tanh(msg_t)) | split(tanh(m_prev))]
    #pragma unroll
    for (int rp = 0; rp < 2; ++rp) {
      const int rr = nr + rp * 32;
      const u16* mp = msgs + ((size_t)(rowBase + rr) * kL + t) * 64 + np * 4;
      const u32 w0 = *(const u32*)mp;
      const u32 w1 = *(const u32*)(mp + 2);
      u16 h0, h1, h2, h3, l0, l1, l2, l3;
      split2(tfast(bf2f((u16)w0)), h0, l0);
      split2(tfast(bf2f((u16)(w0 >> 16))), h1, l1);
      split2(tfast(bf2f((u16)w1)), h2, l2);
      split2(tfast(bf2f((u16)(w1 >> 16))), h3, l3);
      const int o = swz(rr, rr * 128 + np * 4);
      *(u32*)&XMH[o] = (u32)h0 | ((u32)h1 << 16);
      *(u32*)&XMH[o + 2] = (u32)h2 | ((u32)h3 << 16);
      *(u32*)&XML[o] = (u32)l0 | ((u32)l1 << 16);
      *(u32*)&XML[o + 2] = (u32)l2 | ((u32)l3 << 16);

      f32x4 mprev = {0.f, 0.f, 0.f, 0.f};
      if (t > 0)
        mprev = *reinterpret_cast<const f32x4*>(
            carry + (size_t)(rowBase + rr) * 64 + np * 4);
      u16 mh0, mh1, mh2, mh3, ml0, ml1, ml2, ml3;
      split2(tfast(mprev[0]), mh0, ml0); split2(tfast(mprev[1]), mh1, ml1);
      split2(tfast(mprev[2]), mh2, ml2); split2(tfast(mprev[3]), mh3, ml3);
      const int om = swz(rr, rr * 128 + 64 + np * 4);
      *(u32*)&XMH[om] = (u32)mh0 | ((u32)mh1 << 16);
      *(u32*)&XMH[om + 2] = (u32)mh2 | ((u32)mh3 << 16);
      *(u32*)&XML[om] = (u32)ml0 | ((u32)ml1 << 16);
      *(u32*)&XML[om + 2] = (u32)ml2 | ((u32)ml3 << 16);
    }
  }
  __syncthreads();
  {  // p1: A1 -> B1
    TD256x4(OFF_A1, ab1, XMH, XML, 128, B1H, B1L);
  }
  __syncthreads();
  {  // p2: A2 -> B2
    TD256x4(OFF_A2, ab2, B1H, B1L, 256, B2H, B2L);
  }
  __syncthreads();
  {  // p3: a3 (B2 -> out, rows nr & nr+32) + M1 (XM -> B1)
    #pragma unroll
    for (int rp = 0; rp < 2; ++rp) {
      const int rr = nr + rp * 32;
      const int o0 = swz(rr, rr * 256 + np * 16);
      const int o1 = swz(rr, rr * 256 + np * 16 + 8);
      s16x8 d0h = ldsf(B2H + o0), d1h = ldsf(B2H + o1);
      s16x8 d0l = ldsf(B2L + o0), d1l = ldsf(B2L + o1);
      float sum = 0.f;
      #pragma unroll
      for (int j = 0; j < 4; ++j) {
        sum += (bf2f((u16)d0h[j]) + bf2f((u16)d0l[j])) * w3a[j];
        sum += (bf2f((u16)d0h[4 + j]) + bf2f((u16)d0l[4 + j])) * w3b[j];
        sum += (bf2f((u16)d1h[j]) + bf2f((u16)d1l[j])) * w3c[j];
        sum += (bf2f((u16)d1h[4 + j]) + bf2f((u16)d1l[4 + j])) * w3d[j];
      }
      sum += __shfl_xor(sum, 8); sum += __shfl_xor(sum, 4);
      sum += __shfl_xor(sum, 2); sum += __shfl_xor(sum, 1);
      if (np == 0) out[(size_t)(rowBase + rr) * kL + t] = tfast(sum + ab3v);
    }
    TD256x4(OFF_M1, mb1, XMH, XML, 128, B1H, B1L);
  }
  __syncthreads();
  {  // p4: M2 -> B2
    TD256x4(OFF_M2, mb2, B1H, B1L, 256, B2H, B2L);
  }
  __syncthreads();
  {  // p5: M3 -> SMC raw (rows rowh*32 + {0,16}; aliases B1H, B1 dead)
    f32x4 e0 = {0.f, 0.f, 0.f, 0.f}, e1 = e0;
    const u16* Bp_ = wsp + OFF_M3;
    #pragma unroll
    for (int kt = 0; kt < 8; ++kt) {
      const u16* bp_ = Bp_ + (kt * 64 + c64) * 64 + g * 8;
      s16x8 bh = ldsf(bp_), bl = ldsf(bp_ + 32);
      const int r0_ = rowh * 32 + r15;
      const int of0_ = swz(r0_, r0_ * 256 + kt * 32 + g * 8);
      s16x8 a0h = ldsf(B2H + of0_), a0l = ldsf(B2L + of0_);
      e0 = mfma16(a0h, bh, e0);
      e0 = mfma16(a0l, bh, e0);
      e0 = mfma16(a0h, bl, e0);
      const int r1_ = rowh * 32 + 16 + r15;
      const int of1_ = swz(r1_, r1_ * 256 + kt * 32 + g * 8);
      s16x8 a1h = ldsf(B2H + of1_), a1l = ldsf(B2L + of1_);
      e1 = mfma16(a1h, bh, e1);
      e1 = mfma16(a1l, bh, e1);
      e1 = mfma16(a1h, bl, e1);
    }
    #pragma unroll
    for (int i = 0; i < 4; ++i) {
      SMC[(rowh * 32 + g * 4 + i) * 64 + c64] = e0[i] + mb3v;
      SMC[(rowh * 32 + 16 + g * 4 + i) * 64 + c64] = e1[i] + mb3v;
    }
  }
  __syncthreads();
  {  // p6: normalize rows {nr, nr+32} -> carry
    #pragma unroll
    for (int rp = 0; rp < 2; ++rp) {
      const int rr = nr + rp * 32;
      f32x4 v = *reinterpret_cast<const f32x4*>(SMC + rr * 64 + np * 4);
      float ss = v[0]*v[0] + v[1]*v[1] + v[2]*v[2] + v[3]*v[3];
      ss += __shfl_xor(ss, 8); ss += __shfl_xor(ss, 4);
      ss += __shfl_xor(ss, 2); ss += __shfl_xor(ss, 1);
      const float inv = 1.f / fmaxf(sqrtf(ss), 1e-12f);
      f32x4 m;
      m[0] = v[0] * inv; m[1] = v[1] * inv; m[2] = v[2] * inv; m[3] = v[3] * inv;
      *reinterpret_cast<f32x4*>(carry + (size_t)(rowBase + rr) * 64 + np * 4) = m;
    }
  }
}

extern "C" void kernel_launch(void* const* d_in, const int* in_sizes, int n_in,
                              void* d_out, int out_size, void* d_ws, size_t ws_size,
                              hipStream_t stream) {
  (void)in_sizes; (void)n_in; (void)out_size;
  const float* state = (const float*)d_in[0];
  const float* uW1 = (const float*)d_in[1];
  const float* ub1 = (const float*)d_in[2];
  const float* uW2 = (const float*)d_in[3];
  const float* ub2 = (const float*)d_in[4];
  const float* uW3 = (const float*)d_in[5];
  const float* ub3 = (const float*)d_in[6];
  const float* aW1 = (const float*)d_in[7];
  const float* ab1 = (const float*)d_in[8];
  const float* aW2 = (const float*)d_in[9];
  const float* ab2 = (const float*)d_in[10];
  const float* aW3 = (const float*)d_in[11];
  const float* ab3 = (const float*)d_in[12];
  const float* mW1 = (const float*)d_in[13];
  const float* mb1 = (const float*)d_in[14];
  const float* mW2 = (const float*)d_in[15];
  const float* mb2 = (const float*)d_in[16];
  const float* mW3 = (const float*)d_in[17];
  const float* mb3 = (const float*)d_in[18];
  u16* wsp = (u16*)d_ws;
  float* out = (float*)d_out;

  if (ws_size < WS_NEED) return;
  u16* msgs = wsp + MSG_OFF;
  float* carry = reinterpret_cast<float*>(wsp + CD_OFF);

  hipLaunchKernelGGL(prep_kernel, dim3(896), dim3(256), 0, stream,
                     aW1, aW2, mW1, mW2, mW3, uW1, uW2, uW3, wsp);
  for (int t = kL - 1; t >= 0; --t)
    hipLaunchKernelGGL(bu_step_kernel, dim3(kB / 32), dim3(512), 0, stream,
                       state, ub1, ub2, ub3, wsp, msgs, carry, t);
  for (int t = 0; t < kL; ++t)
    hipLaunchKernelGGL(td_step_kernel, dim3(kB / 64), dim3(512), 0, stream,
                       ab1, ab2, aW3, ab3, mb1, mb2, mb3,
                       wsp, msgs, carry, out, t);
}

// Round 17
// 1207.303 us; speedup vs baseline: 1.4037x; 1.0153x over previous
//
#include <hip/hip_runtime.h>

typedef unsigned int u32;
typedef unsigned short u16;
typedef short s16x8 __attribute__((ext_vector_type(8)));
typedef float f32x4 __attribute__((ext_vector_type(4)));

namespace {
constexpr int kB = 16384, kL = 20;

// packed split-bf16 weights in d_ws (u16 elems). per (kt,n): hi[32] | lo[32]
constexpr int OFF_A1 = 0;                       // 128x256
constexpr int OFF_A2 = OFF_A1 + 128 * 256 * 2;  // 256x256
constexpr int OFF_M1 = OFF_A2 + 256 * 256 * 2;  // 128x256
constexpr int OFF_M2 = OFF_M1 + 128 * 256 * 2;  // 256x256
constexpr int OFF_M3 = OFF_M2 + 256 * 256 * 2;  // 256x64
constexpr int OFF_U1 = OFF_M3 + 256 * 64 * 2;   // 64x64
constexpr int OFF_U2 = OFF_U1 + 64 * 64 * 2;    // 128x64
constexpr int OFF_U3 = OFF_U2 + 128 * 64 * 2;   // 64x64
constexpr int PACK_ELEMS = OFF_U3 + 64 * 64 * 2;        // 458752 u16
constexpr size_t MSG_OFF = (size_t)PACK_ELEMS;          // bf16 msgs [b][t][64]
constexpr size_t CD_OFF = MSG_OFF + (size_t)kB * kL * 64;  // f32 carry [b][64]
constexpr size_t WS_NEED = (CD_OFF + (size_t)kB * 64 * 2) * 2;  // ~47 MB

__device__ __forceinline__ u16 f2bf(float x) {
  u32 b = __builtin_bit_cast(u32, x);
  b += 0x7FFFu + ((b >> 16) & 1u);
  return (u16)(b >> 16);
}
__device__ __forceinline__ float bf2f(u16 h) {
  return __builtin_bit_cast(float, (u32)h << 16);
}
__device__ __forceinline__ void split2(float x, u16& hi, u16& lo) {
  hi = f2bf(x);
  lo = f2bf(x - bf2f(hi));
}
__device__ __forceinline__ f32x4 mfma16(s16x8 a, s16x8 b, f32x4 c) {
  return __builtin_amdgcn_mfma_f32_16x16x32_bf16(a, b, c, 0, 0, 0);
}
__device__ __forceinline__ s16x8 ldsf(const u16* p) {
  return *reinterpret_cast<const s16x8*>(p);
}
__device__ __forceinline__ int swz(int row, int idx) { return idx ^ ((row & 7) << 3); }

__device__ __forceinline__ float fast_rcp(float x) {
#if __has_builtin(__builtin_amdgcn_rcpf)
  return __builtin_amdgcn_rcpf(x);
#else
  return 1.0f / x;
#endif
}
__device__ __forceinline__ float tfast(float x) {  // tanh, |err| ~1e-6
#if __has_builtin(__builtin_amdgcn_exp2f)
  float e = __builtin_amdgcn_exp2f(x * 2.8853900817779268f);
#else
  float e = exp2f(x * 2.8853900817779268f);
#endif
  return fmaf(-2.0f, fast_rcp(e + 1.0f), 1.0f);
}
}  // namespace

// epilogue: write 4 acc elems (relu + split) to 256-wide swizzled planes
#define EPI4(A, BB, MB, COL, DH, DL)                                         \
  {                                                                          \
    _Pragma("unroll") for (int i_ = 0; i_ < 4; ++i_) {                       \
      const int row_ = (MB) + g * 4 + i_;                                    \
      u16 h_, l_;                                                            \
      split2(fmaxf((A)[i_] + (BB), 0.f), h_, l_);                            \
      const int o_ = swz(row_, row_ * 256 + (COL));                          \
      (DH)[o_] = h_;                                                         \
      (DL)[o_] = l_;                                                         \
    }                                                                        \
  }

// 256-col layer, RPB=64, single col-tile per pass (NT=1, NM=4, low pressure).
// CB = column base for this pass (this lane's col = CB + r15).
#define TD256P(OFFW, BIAS, AH, AL, LDA, DH, DL, CB)                          \
  {                                                                          \
    f32x4 c0 = {0.f, 0.f, 0.f, 0.f}, c1 = c0, c2 = c0, c3 = c0;              \
    const u16* Bp_ = wsp + (OFFW);                                           \
    const int cc_ = (CB) + r15;                                              \
    _Pragma("unroll") for (int kt = 0; kt < (LDA) / 32; ++kt) {              \
      const u16* bp_ = Bp_ + (kt * 256 + cc_) * 64 + g * 8;                  \
      s16x8 bh = ldsf(bp_), bl = ldsf(bp_ + 32);                             \
      {                                                                      \
        const int r_ = r15;                                                  \
        const int of_ = swz(r_, r_ * (LDA) + kt * 32 + g * 8);               \
        s16x8 ah = ldsf((AH) + of_), al = ldsf((AL) + of_);                  \
        c0 = mfma16(ah, bh, c0);                                             \
        c0 = mfma16(al, bh, c0);                                             \
        c0 = mfma16(ah, bl, c0);                                             \
      }                                                                      \
      {                                                                      \
        const int r_ = 16 + r15;                                             \
        const int of_ = swz(r_, r_ * (LDA) + kt * 32 + g * 8);               \
        s16x8 ah = ldsf((AH) + of_), al = ldsf((AL) + of_);                  \
        c1 = mfma16(ah, bh, c1);                                             \
        c1 = mfma16(al, bh, c1);                                             \
        c1 = mfma16(ah, bl, c1);                                             \
      }                                                                      \
      {                                                                      \
        const int r_ = 32 + r15;                                             \
        const int of_ = swz(r_, r_ * (LDA) + kt * 32 + g * 8);               \
        s16x8 ah = ldsf((AH) + of_), al = ldsf((AL) + of_);                  \
        c2 = mfma16(ah, bh, c2);                                             \
        c2 = mfma16(al, bh, c2);                                             \
        c2 = mfma16(ah, bl, c2);                                             \
      }                                                                      \
      {                                                                      \
        const int r_ = 48 + r15;                                             \
        const int of_ = swz(r_, r_ * (LDA) + kt * 32 + g * 8);               \
        s16x8 ah = ldsf((AH) + of_), al = ldsf((AL) + of_);                  \
        c3 = mfma16(ah, bh, c3);                                             \
        c3 = mfma16(al, bh, c3);                                             \
        c3 = mfma16(ah, bl, c3);                                             \
      }                                                                      \
    }                                                                        \
    const float bb_ = (BIAS)[cc_];                                           \
    EPI4(c0, bb_, 0, cc_, DH, DL);                                           \
    EPI4(c1, bb_, 16, cc_, DH, DL);                                          \
    EPI4(c2, bb_, 32, cc_, DH, DL);                                          \
    EPI4(c3, bb_, 48, cc_, DH, DL);                                          \
  }

// 64-col layer for BU (RPB=32): row ROWQ*16+r15, col c64, K=KK
#define MM64(OFFW, KK, AH, AL, LDA, ROWQ)                                    \
  f32x4 acc64 = {0.f, 0.f, 0.f, 0.f};                                        \
  {                                                                          \
    const u16* Bp_ = wsp + (OFFW);                                           \
    _Pragma("unroll") for (int kt = 0; kt < (KK) / 32; ++kt) {               \
      const u16* bp_ = Bp_ + (kt * 64 + c64) * 64 + g * 8;                   \
      s16x8 bh = ldsf(bp_), bl = ldsf(bp_ + 32);                             \
      const int ra_ = (ROWQ) * 16 + r15;                                     \
      const int ofa_ = swz(ra_, ra_ * (LDA) + kt * 32 + g * 8);              \
      s16x8 ah = ldsf((AH) + ofa_), al = ldsf((AL) + ofa_);                  \
      acc64 = mfma16(ah, bh, acc64);                                         \
      acc64 = mfma16(al, bh, acc64);                                         \
      acc64 = mfma16(ah, bl, acc64);                                         \
    }                                                                        \
  }

// ---------------- prep: pack weights into split-bf16 frag layout ----------------
__global__ __launch_bounds__(256) void prep_kernel(
    const float* __restrict__ aW1, const float* __restrict__ aW2,
    const float* __restrict__ mW1, const float* __restrict__ mW2,
    const float* __restrict__ mW3, const float* __restrict__ uW1,
    const float* __restrict__ uW2, const float* __restrict__ uW3,
    u16* __restrict__ ws) {
  const float* Ws[8] = {aW1, aW2, mW1, mW2, mW3, uW1, uW2, uW3};
  const int Ns[8]  = {256, 256, 256, 256, 64, 64, 64, 64};
  const int dst[8] = {OFF_A1, OFF_A2, OFF_M1, OFF_M2, OFF_M3, OFF_U1, OFF_U2, OFF_U3};
  const int cnt[8] = {32768, 65536, 32768, 65536, 16384, 4096, 8192, 4096};
  const int total = 229376;
  for (int e = blockIdx.x * 256 + threadIdx.x; e < total; e += gridDim.x * 256) {
    int l = 0, base = 0;
    while (e - base >= cnt[l]) { base += cnt[l]; ++l; }
    const int s = e - base, N = Ns[l];
    const int k = s / N, n = s % N;
    u16 hi, lo;
    split2(Ws[l][s], hi, lo);
    const int ob = dst[l] + ((k >> 5) * N + n) * 64 + (k & 31);
    ws[ob] = hi;
    ws[ob + 32] = lo;
  }
}

// ---------------- BU step t (RPB=32, 512 thr, clean) ----------------
__global__ __launch_bounds__(512) void bu_step_kernel(
    const float* __restrict__ state,
    const float* __restrict__ ub1, const float* __restrict__ ub2,
    const float* __restrict__ ub3,
    const u16* __restrict__ wsp, u16* __restrict__ msgs,
    float* __restrict__ carry, int t) {
  __shared__ __align__(16) u16 lds[20480];  // 40 KB
  u16* XSH = lds;                // 32x64
  u16* XSL = lds + 2048;
  u16* XMH = lds + 4096;         // 32x128
  u16* XML = lds + 8192;
  u16* H2H = lds + 12288;        // 32x64
  u16* H2L = lds + 14336;
  float* SMC = reinterpret_cast<float*>(lds + 16384);  // 32x64 f32

  const int tid = threadIdx.x;
  const int wv = tid >> 6, lane = tid & 63;
  const int r15 = lane & 15, g = lane >> 4;
  const int nq = wv & 3;
  const int rowq = wv >> 2;
  const int nr = tid >> 4, np = tid & 15;
  const int rowBase = blockIdx.x * 32;
  const int c64 = nq * 16 + r15;
  const float ub1v = ub1[c64], ub2v = ub2[c64], ub3v = ub3[c64];

  {  // s0: stage state(t) -> XS ; XM[64:] = split(tanh(m_prev))
    f32x4 v = *reinterpret_cast<const f32x4*>(
        state + ((size_t)(rowBase + nr) * kL + t) * 64 + np * 4);
    u16 h0, h1, h2, h3, l0, l1, l2, l3;
    split2(v[0], h0, l0); split2(v[1], h1, l1);
    split2(v[2], h2, l2); split2(v[3], h3, l3);
    const int o = swz(nr, nr * 64 + np * 4);
    *(u32*)&XSH[o] = (u32)h0 | ((u32)h1 << 16);
    *(u32*)&XSH[o + 2] = (u32)h2 | ((u32)h3 << 16);
    *(u32*)&XSL[o] = (u32)l0 | ((u32)l1 << 16);
    *(u32*)&XSL[o + 2] = (u32)l2 | ((u32)l3 << 16);

    f32x4 mp = {0.f, 0.f, 0.f, 0.f};
    if (t < kL - 1)
      mp = *reinterpret_cast<const f32x4*>(carry + (size_t)(rowBase + nr) * 64 + np * 4);
    u16 mh0, mh1, mh2, mh3, ml0, ml1, ml2, ml3;
    split2(tfast(mp[0]), mh0, ml0); split2(tfast(mp[1]), mh1, ml1);
    split2(tfast(mp[2]), mh2, ml2); split2(tfast(mp[3]), mh3, ml3);
    const int om = swz(nr, nr * 128 + 64 + np * 4);
    *(u32*)&XMH[om] = (u32)mh0 | ((u32)mh1 << 16);
    *(u32*)&XMH[om + 2] = (u32)mh2 | ((u32)mh3 << 16);
    *(u32*)&XML[om] = (u32)ml0 | ((u32)ml1 << 16);
    *(u32*)&XML[om + 2] = (u32)ml2 | ((u32)ml3 << 16);
  }
  __syncthreads();
  {  // s1: U1 -> SMC raw
    MM64(OFF_U1, 64, XSH, XSL, 64, rowq);
    #pragma unroll
    for (int i = 0; i < 4; ++i)
      SMC[(rowq * 16 + g * 4 + i) * 64 + c64] = acc64[i] + ub1v;
  }
  __syncthreads();
  {  // s2: normalize + tanh -> XM[0:64]
    f32x4 v = *reinterpret_cast<const f32x4*>(SMC + nr * 64 + np * 4);
    float ss = v[0]*v[0] + v[1]*v[1] + v[2]*v[2] + v[3]*v[3];
    ss += __shfl_xor(ss, 8); ss += __shfl_xor(ss, 4);
    ss += __shfl_xor(ss, 2); ss += __shfl_xor(ss, 1);
    const float inv = 1.f / fmaxf(sqrtf(ss), 1e-12f);
    u16 h0, h1, h2, h3, l0, l1, l2, l3;
    split2(tfast(v[0] * inv), h0, l0); split2(tfast(v[1] * inv), h1, l1);
    split2(tfast(v[2] * inv), h2, l2); split2(tfast(v[3] * inv), h3, l3);
    const int o = swz(nr, nr * 128 + np * 4);
    *(u32*)&XMH[o] = (u32)h0 | ((u32)h1 << 16);
    *(u32*)&XMH[o + 2] = (u32)h2 | ((u32)h3 << 16);
    *(u32*)&XML[o] = (u32)l0 | ((u32)l1 << 16);
    *(u32*)&XML[o + 2] = (u32)l2 | ((u32)l3 << 16);
  }
  __syncthreads();
  {  // s3: U2 (K=128) -> tanh -> H2
    MM64(OFF_U2, 128, XMH, XML, 128, rowq);
    #pragma unroll
    for (int i = 0; i < 4; ++i) {
      u16 hh, ll;
      split2(tfast(acc64[i] + ub2v), hh, ll);
      const int row = rowq * 16 + g * 4 + i;
      const int o = swz(row, row * 64 + c64);
      H2H[o] = hh; H2L[o] = ll;
    }
  }
  __syncthreads();
  {  // s4: U3 -> SMC raw
    MM64(OFF_U3, 64, H2H, H2L, 64, rowq);
    #pragma unroll
    for (int i = 0; i < 4; ++i)
      SMC[(rowq * 16 + g * 4 + i) * 64 + c64] = acc64[i] + ub3v;
  }
  __syncthreads();
  {  // s5: normalize -> msg: store bf16 msgs[b][t] + f32 carry
    f32x4 v = *reinterpret_cast<const f32x4*>(SMC + nr * 64 + np * 4);
    float ss = v[0]*v[0] + v[1]*v[1] + v[2]*v[2] + v[3]*v[3];
    ss += __shfl_xor(ss, 8); ss += __shfl_xor(ss, 4);
    ss += __shfl_xor(ss, 2); ss += __shfl_xor(ss, 1);
    const float inv = 1.f / fmaxf(sqrtf(ss), 1e-12f);
    f32x4 m;
    m[0] = v[0] * inv; m[1] = v[1] * inv; m[2] = v[2] * inv; m[3] = v[3] * inv;
    u16* mp = msgs + ((size_t)(rowBase + nr) * kL + t) * 64 + np * 4;
    *(u32*)mp = (u32)f2bf(m[0]) | ((u32)f2bf(m[1]) << 16);
    *(u32*)(mp + 2) = (u32)f2bf(m[2]) | ((u32)f2bf(m[3]) << 16);
    *reinterpret_cast<f32x4*>(carry + (size_t)(rowBase + nr) * 64 + np * 4) = m;
  }
}

// -------- TD step t: RPB=64, 512 thr, NT=1/NM=4, two col passes --------
__global__ __launch_bounds__(512) void td_step_kernel(
    const float* __restrict__ ab1, const float* __restrict__ ab2,
    const float* __restrict__ aW3, const float* __restrict__ ab3,
    const float* __restrict__ mb1, const float* __restrict__ mb2,
    const float* __restrict__ mb3,
    const u16* __restrict__ wsp, const u16* __restrict__ msgs,
    float* __restrict__ carry, float* __restrict__ out, int t) {
  __shared__ __align__(16) u16 lds[81920];  // 160 KB
  u16* XMH = lds;             // 64x128
  u16* XML = lds + 8192;
  u16* B1H = lds + 16384;     // 64x256
  u16* B1L = lds + 32768;
  u16* B2H = lds + 49152;     // 64x256
  u16* B2L = lds + 65536;
  float* SMC = reinterpret_cast<float*>(B1H);  // 64x64 f32, B1 dead after M2

  const int tid = threadIdx.x;
  const int wv = tid >> 6, lane = tid & 63;
  const int r15 = lane & 15, g = lane >> 4;
  const int nq = wv & 3, rowh = wv >> 2;     // M3: 4 col-tiles x 2 row-halves
  const int nr = tid >> 4, np = tid & 15;    // 32 rows x 16 lanes (x2 row passes)
  const int rowBase = blockIdx.x * 64;
  const int cA = wv * 16;                    // pass-0 col base; pass-1 = cA+128
  const int c64 = nq * 16 + r15;

  {  // p0: XM rows {nr, nr+32} = [split(tanh(msg_t)) | split(tanh(m_prev))]
    #pragma unroll
    for (int rp = 0; rp < 2; ++rp) {
      const int rr = nr + rp * 32;
      const u16* mp = msgs + ((size_t)(rowBase + rr) * kL + t) * 64 + np * 4;
      const u32 w0 = *(const u32*)mp;
      const u32 w1 = *(const u32*)(mp + 2);
      u16 h0, h1, h2, h3, l0, l1, l2, l3;
      split2(tfast(bf2f((u16)w0)), h0, l0);
      split2(tfast(bf2f((u16)(w0 >> 16))), h1, l1);
      split2(tfast(bf2f((u16)w1)), h2, l2);
      split2(tfast(bf2f((u16)(w1 >> 16))), h3, l3);
      const int o = swz(rr, rr * 128 + np * 4);
      *(u32*)&XMH[o] = (u32)h0 | ((u32)h1 << 16);
      *(u32*)&XMH[o + 2] = (u32)h2 | ((u32)h3 << 16);
      *(u32*)&XML[o] = (u32)l0 | ((u32)l1 << 16);
      *(u32*)&XML[o + 2] = (u32)l2 | ((u32)l3 << 16);

      f32x4 mprev = {0.f, 0.f, 0.f, 0.f};
      if (t > 0)
        mprev = *reinterpret_cast<const f32x4*>(
            carry + (size_t)(rowBase + rr) * 64 + np * 4);
      u16 mh0, mh1, mh2, mh3, ml0, ml1, ml2, ml3;
      split2(tfast(mprev[0]), mh0, ml0); split2(tfast(mprev[1]), mh1, ml1);
      split2(tfast(mprev[2]), mh2, ml2); split2(tfast(mprev[3]), mh3, ml3);
      const int om = swz(rr, rr * 128 + 64 + np * 4);
      *(u32*)&XMH[om] = (u32)mh0 | ((u32)mh1 << 16);
      *(u32*)&XMH[om + 2] = (u32)mh2 | ((u32)mh3 << 16);
      *(u32*)&XML[om] = (u32)ml0 | ((u32)ml1 << 16);
      *(u32*)&XML[om + 2] = (u32)ml2 | ((u32)ml3 << 16);
    }
  }
  __syncthreads();
  {  // p1: A1 -> B1 (two col passes)
    TD256P(OFF_A1, ab1, XMH, XML, 128, B1H, B1L, cA);
    TD256P(OFF_A1, ab1, XMH, XML, 128, B1H, B1L, cA + 128);
  }
  __syncthreads();
  {  // p2: A2 -> B2
    TD256P(OFF_A2, ab2, B1H, B1L, 256, B2H, B2L, cA);
    TD256P(OFF_A2, ab2, B1H, B1L, 256, B2H, B2L, cA + 128);
  }
  __syncthreads();
  {  // p3: a3 (B2 -> out, rows nr & nr+32) + M1 (XM -> B1)
    {
      const f32x4 w3a = *reinterpret_cast<const f32x4*>(aW3 + np * 16);
      const f32x4 w3b = *reinterpret_cast<const f32x4*>(aW3 + np * 16 + 4);
      const f32x4 w3c = *reinterpret_cast<const f32x4*>(aW3 + np * 16 + 8);
      const f32x4 w3d = *reinterpret_cast<const f32x4*>(aW3 + np * 16 + 12);
      const float ab3v = ab3[0];
      #pragma unroll
      for (int rp = 0; rp < 2; ++rp) {
        const int rr = nr + rp * 32;
        const int o0 = swz(rr, rr * 256 + np * 16);
        const int o1 = swz(rr, rr * 256 + np * 16 + 8);
        s16x8 d0h = ldsf(B2H + o0), d1h = ldsf(B2H + o1);
        s16x8 d0l = ldsf(B2L + o0), d1l = ldsf(B2L + o1);
        float sum = 0.f;
        #pragma unroll
        for (int j = 0; j < 4; ++j) {
          sum += (bf2f((u16)d0h[j]) + bf2f((u16)d0l[j])) * w3a[j];
          sum += (bf2f((u16)d0h[4 + j]) + bf2f((u16)d0l[4 + j])) * w3b[j];
          sum += (bf2f((u16)d1h[j]) + bf2f((u16)d1l[j])) * w3c[j];
          sum += (bf2f((u16)d1h[4 + j]) + bf2f((u16)d1l[4 + j])) * w3d[j];
        }
        sum += __shfl_xor(sum, 8); sum += __shfl_xor(sum, 4);
        sum += __shfl_xor(sum, 2); sum += __shfl_xor(sum, 1);
        if (np == 0) out[(size_t)(rowBase + rr) * kL + t] = tfast(sum + ab3v);
      }
    }
    TD256P(OFF_M1, mb1, XMH, XML, 128, B1H, B1L, cA);
    TD256P(OFF_M1, mb1, XMH, XML, 128, B1H, B1L, cA + 128);
  }
  __syncthreads();
  {  // p4: M2 -> B2
    TD256P(OFF_M2, mb2, B1H, B1L, 256, B2H, B2L, cA);
    TD256P(OFF_M2, mb2, B1H, B1L, 256, B2H, B2L, cA + 128);
  }
  __syncthreads();
  {  // p5: M3 -> SMC raw (rows rowh*32 + {0,16}; aliases B1H, B1 dead)
    const float mb3v = mb3[c64];
    f32x4 e0 = {0.f, 0.f, 0.f, 0.f}, e1 = e0;
    const u16* Bp_ = wsp + OFF_M3;
    #pragma unroll
    for (int kt = 0; kt < 8; ++kt) {
      const u16* bp_ = Bp_ + (kt * 64 + c64) * 64 + g * 8;
      s16x8 bh = ldsf(bp_), bl = ldsf(bp_ + 32);
      const int r0_ = rowh * 32 + r15;
      const int of0_ = swz(r0_, r0_ * 256 + kt * 32 + g * 8);
      s16x8 a0h = ldsf(B2H + of0_), a0l = ldsf(B2L + of0_);
      e0 = mfma16(a0h, bh, e0);
      e0 = mfma16(a0l, bh, e0);
      e0 = mfma16(a0h, bl, e0);
      const int r1_ = rowh * 32 + 16 + r15;
      const int of1_ = swz(r1_, r1_ * 256 + kt * 32 + g * 8);
      s16x8 a1h = ldsf(B2H + of1_), a1l = ldsf(B2L + of1_);
      e1 = mfma16(a1h, bh, e1);
      e1 = mfma16(a1l, bh, e1);
      e1 = mfma16(a1h, bl, e1);
    }
    #pragma unroll
    for (int i = 0; i < 4; ++i) {
      SMC[(rowh * 32 + g * 4 + i) * 64 + c64] = e0[i] + mb3v;
      SMC[(rowh * 32 + 16 + g * 4 + i) * 64 + c64] = e1[i] + mb3v;
    }
  }
  __syncthreads();
  {  // p6: normalize rows {nr, nr+32} -> carry
    #pragma unroll
    for (int rp = 0; rp < 2; ++rp) {
      const int rr = nr + rp * 32;
      f32x4 v = *reinterpret_cast<const f32x4*>(SMC + rr * 64 + np * 4);
      float ss = v[0]*v[0] + v[1]*v[1] + v[2]*v[2] + v[3]*v[3];
      ss += __shfl_xor(ss, 8); ss += __shfl_xor(ss, 4);
      ss += __shfl_xor(ss, 2); ss += __shfl_xor(ss, 1);
      const float inv = 1.f / fmaxf(sqrtf(ss), 1e-12f);
      f32x4 m;
      m[0] = v[0] * inv; m[1] = v[1] * inv; m[2] = v[2] * inv; m[3] = v[3] * inv;
      *reinterpret_cast<f32x4*>(carry + (size_t)(rowBase + rr) * 64 + np * 4) = m;
    }
  }
}

extern "C" void kernel_launch(void* const* d_in, const int* in_sizes, int n_in,
                              void* d_out, int out_size, void* d_ws, size_t ws_size,
                              hipStream_t stream) {
  (void)in_sizes; (void)n_in; (void)out_size;
  const float* state = (const float*)d_in[0];
  const float* uW1 = (const float*)d_in[1];
  const float* ub1 = (const float*)d_in[2];
  const float* uW2 = (const float*)d_in[3];
  const float* ub2 = (const float*)d_in[4];
  const float* uW3 = (const float*)d_in[5];
  const float* ub3 = (const float*)d_in[6];
  const float* aW1 = (const float*)d_in[7];
  const float* ab1 = (const float*)d_in[8];
  const float* aW2 = (const float*)d_in[9];
  const float* ab2 = (const float*)d_in[10];
  const float* aW3 = (const float*)d_in[11];
  const float* ab3 = (const float*)d_in[12];
  const float* mW1 = (const float*)d_in[13];
  const float* mb1 = (const float*)d_in[14];
  const float* mW2 = (const float*)d_in[15];
  const float* mb2 = (const float*)d_in[16];
  const float* mW3 = (const float*)d_in[17];
  const float* mb3 = (const float*)d_in[18];
  u16* wsp = (u16*)d_ws;
  float* out = (float*)d_out;

  if (ws_size < WS_NEED) return;
  u16* msgs = wsp + MSG_OFF;
  float* carry = reinterpret_cast<float*>(wsp + CD_OFF);

  hipLaunchKernelGGL(prep_kernel, dim3(896), dim3(256), 0, stream,
                     aW1, aW2, mW1, mW2, mW3, uW1, uW2, uW3, wsp);
  for (int t = kL - 1; t >= 0; --t)
    hipLaunchKernelGGL(bu_step_kernel, dim3(kB / 32), dim3(512), 0, stream,
                       state, ub1, ub2, ub3, wsp, msgs, carry, t);
  for (int t = 0; t < kL; ++t)
    hipLaunchKernelGGL(td_step_kernel, dim3(kB / 64), dim3(512), 0, stream,
                       ab1, ab2, aW3, ab3, mb1, mb2, mb3,
                       wsp, msgs, carry, out, t);
}

// Round 18
// 843.067 us; speedup vs baseline: 2.0101x; 1.4320x over previous
//
#include <hip/hip_runtime.h>

typedef unsigned int u32;
typedef unsigned short u16;
typedef short s16x8 __attribute__((ext_vector_type(8)));
typedef float f32x4 __attribute__((ext_vector_type(4)));

namespace {
constexpr int kB = 16384, kL = 20;

// packed split-bf16 weights in d_ws (u16 elems). per (kt,n): hi[32] | lo[32]
constexpr int OFF_A1 = 0;                       // 128x256
constexpr int OFF_A2 = OFF_A1 + 128 * 256 * 2;  // 256x256
constexpr int OFF_M1 = OFF_A2 + 256 * 256 * 2;  // 128x256
constexpr int OFF_M2 = OFF_M1 + 128 * 256 * 2;  // 256x256
constexpr int OFF_M3 = OFF_M2 + 256 * 256 * 2;  // 256x64
constexpr int OFF_U1 = OFF_M3 + 256 * 64 * 2;   // 64x64
constexpr int OFF_U2 = OFF_U1 + 64 * 64 * 2;    // 128x64
constexpr int OFF_U3 = OFF_U2 + 128 * 64 * 2;   // 64x64
constexpr int PACK_ELEMS = OFF_U3 + 64 * 64 * 2;        // 458752 u16
constexpr size_t MSG_OFF = (size_t)PACK_ELEMS;          // bf16 msgs [b][t][64]
constexpr size_t CD_OFF = MSG_OFF + (size_t)kB * kL * 64;  // f32 carry [b][64]
constexpr size_t WS_NEED = (CD_OFF + (size_t)kB * 64 * 2) * 2;  // ~47 MB

__device__ __forceinline__ u16 f2bf(float x) {
  u32 b = __builtin_bit_cast(u32, x);
  b += 0x7FFFu + ((b >> 16) & 1u);
  return (u16)(b >> 16);
}
__device__ __forceinline__ float bf2f(u16 h) {
  return __builtin_bit_cast(float, (u32)h << 16);
}
__device__ __forceinline__ void split2(float x, u16& hi, u16& lo) {
  hi = f2bf(x);
  lo = f2bf(x - bf2f(hi));
}
__device__ __forceinline__ f32x4 mfma16(s16x8 a, s16x8 b, f32x4 c) {
  return __builtin_amdgcn_mfma_f32_16x16x32_bf16(a, b, c, 0, 0, 0);
}
__device__ __forceinline__ s16x8 ldsf(const u16* p) {
  return *reinterpret_cast<const s16x8*>(p);
}
__device__ __forceinline__ int swz(int row, int idx) { return idx ^ ((row & 7) << 3); }

__device__ __forceinline__ float fast_rcp(float x) {
#if __has_builtin(__builtin_amdgcn_rcpf)
  return __builtin_amdgcn_rcpf(x);
#else
  return 1.0f / x;
#endif
}
__device__ __forceinline__ float tfast(float x) {  // tanh, |err| ~1e-6
#if __has_builtin(__builtin_amdgcn_exp2f)
  float e = __builtin_amdgcn_exp2f(x * 2.8853900817779268f);
#else
  float e = exp2f(x * 2.8853900817779268f);
#endif
  return fmaf(-2.0f, fast_rcp(e + 1.0f), 1.0f);
}
}  // namespace

// epilogue: write 4 acc elems (relu + split) to 256-wide swizzled planes
#define EPI4(A, BB, MB, COL, DH, DL)                                         \
  {                                                                          \
    _Pragma("unroll") for (int i_ = 0; i_ < 4; ++i_) {                       \
      const int row_ = (MB) + g * 4 + i_;                                    \
      u16 h_, l_;                                                            \
      split2(fmaxf((A)[i_] + (BB), 0.f), h_, l_);                            \
      const int o_ = swz(row_, row_ * 256 + (COL));                          \
      (DH)[o_] = h_;                                                         \
      (DL)[o_] = l_;                                                         \
    }                                                                        \
  }

// 6 MFMAs for one 16-row tile against B regs bh/bl
#define ROW6(C, RB, AH, AL, LDA, KT)                                         \
  {                                                                          \
    const int r_ = (RB) + r15;                                               \
    const int of_ = swz(r_, r_ * (LDA) + (KT) * 32 + g * 8);                 \
    s16x8 ah = ldsf((AH) + of_), al = ldsf((AL) + of_);                      \
    C = mfma16(ah, bh, C);                                                   \
    C = mfma16(al, bh, C);                                                   \
    C = mfma16(ah, bl, C);                                                   \
  }

// 256-col layer, RPB=64, NT=1/NM=4, 1-deep pinned B prefetch pipeline.
#define TD256P(OFFW, BIAS, AH, AL, LDA, DH, DL, CB)                          \
  {                                                                          \
    f32x4 c0 = {0.f, 0.f, 0.f, 0.f}, c1 = c0, c2 = c0, c3 = c0;              \
    const u16* Bp_ = wsp + (OFFW);                                           \
    const int cc_ = (CB) + r15;                                              \
    s16x8 pbh = ldsf(Bp_ + (size_t)cc_ * 64 + g * 8);                        \
    s16x8 pbl = ldsf(Bp_ + (size_t)cc_ * 64 + g * 8 + 32);                   \
    _Pragma("unroll") for (int kt = 0; kt < (LDA) / 32; ++kt) {              \
      s16x8 bh = pbh, bl = pbl;                                              \
      if (kt + 1 < (LDA) / 32) {                                             \
        const u16* nb_ = Bp_ + ((kt + 1) * 256 + cc_) * 64 + g * 8;          \
        pbh = ldsf(nb_);                                                     \
        pbl = ldsf(nb_ + 32);                                                \
      }                                                                      \
      __builtin_amdgcn_sched_barrier(0);                                     \
      ROW6(c0, 0, AH, AL, LDA, kt);                                          \
      ROW6(c1, 16, AH, AL, LDA, kt);                                         \
      ROW6(c2, 32, AH, AL, LDA, kt);                                         \
      ROW6(c3, 48, AH, AL, LDA, kt);                                         \
    }                                                                        \
    const float bb_ = (BIAS)[cc_];                                           \
    EPI4(c0, bb_, 0, cc_, DH, DL);                                           \
    EPI4(c1, bb_, 16, cc_, DH, DL);                                          \
    EPI4(c2, bb_, 32, cc_, DH, DL);                                          \
    EPI4(c3, bb_, 48, cc_, DH, DL);                                          \
  }

// 64-col layer (BU): row ROWQ*16+r15, col c64, K=KK
#define MM64(OFFW, KK, AH, AL, LDA, ROWQ)                                    \
  f32x4 acc64 = {0.f, 0.f, 0.f, 0.f};                                        \
  {                                                                          \
    const u16* Bp_ = wsp + (OFFW);                                           \
    _Pragma("unroll") for (int kt = 0; kt < (KK) / 32; ++kt) {               \
      const u16* bp_ = Bp_ + (kt * 64 + c64) * 64 + g * 8;                   \
      s16x8 bh = ldsf(bp_), bl = ldsf(bp_ + 32);                             \
      const int ra_ = (ROWQ) * 16 + r15;                                     \
      const int ofa_ = swz(ra_, ra_ * (LDA) + kt * 32 + g * 8);              \
      s16x8 ah = ldsf((AH) + ofa_), al = ldsf((AL) + ofa_);                  \
      acc64 = mfma16(ah, bh, acc64);                                         \
      acc64 = mfma16(al, bh, acc64);                                         \
      acc64 = mfma16(ah, bl, acc64);                                         \
    }                                                                        \
  }

// ---------------- prep: pack weights into split-bf16 frag layout ----------------
__global__ __launch_bounds__(256) void prep_kernel(
    const float* __restrict__ aW1, const float* __restrict__ aW2,
    const float* __restrict__ mW1, const float* __restrict__ mW2,
    const float* __restrict__ mW3, const float* __restrict__ uW1,
    const float* __restrict__ uW2, const float* __restrict__ uW3,
    u16* __restrict__ ws) {
  const float* Ws[8] = {aW1, aW2, mW1, mW2, mW3, uW1, uW2, uW3};
  const int Ns[8]  = {256, 256, 256, 256, 64, 64, 64, 64};
  const int dst[8] = {OFF_A1, OFF_A2, OFF_M1, OFF_M2, OFF_M3, OFF_U1, OFF_U2, OFF_U3};
  const int cnt[8] = {32768, 65536, 32768, 65536, 16384, 4096, 8192, 4096};
  const int total = 229376;
  for (int e = blockIdx.x * 256 + threadIdx.x; e < total; e += gridDim.x * 256) {
    int l = 0, base = 0;
    while (e - base >= cnt[l]) { base += cnt[l]; ++l; }
    const int s = e - base, N = Ns[l];
    const int k = s / N, n = s % N;
    u16 hi, lo;
    split2(Ws[l][s], hi, lo);
    const int ob = dst[l] + ((k >> 5) * N + n) * 64 + (k & 31);
    ws[ob] = hi;
    ws[ob + 32] = lo;
  }
}

// ------- BU all steps fused: RPB=32, 512 thr, m-state lives in XM LDS -------
__global__ __launch_bounds__(512) void bu_all_kernel(
    const float* __restrict__ state,
    const float* __restrict__ ub1, const float* __restrict__ ub2,
    const float* __restrict__ ub3,
    const u16* __restrict__ wsp, u16* __restrict__ msgs) {
  __shared__ __align__(16) u16 lds[20480];  // 40 KB -> 4 blocks/CU
  u16* XSH = lds;                // 32x64
  u16* XSL = lds + 2048;
  u16* XMH = lds + 4096;         // 32x128
  u16* XML = lds + 8192;
  u16* H2H = lds + 12288;        // 32x64
  u16* H2L = lds + 14336;
  float* SMC = reinterpret_cast<float*>(lds + 16384);  // 32x64 f32

  const int tid = threadIdx.x;
  const int wv = tid >> 6, lane = tid & 63;
  const int r15 = lane & 15, g = lane >> 4;
  const int nq = wv & 3;
  const int rowq = wv >> 2;
  const int nr = tid >> 4, np = tid & 15;
  const int rowBase = blockIdx.x * 32;
  const int c64 = nq * 16 + r15;
  const float ub1v = ub1[c64], ub2v = ub2[c64], ub3v = ub3[c64];

  {  // init: m-state (XM[64:]) = split(tanh(0)) = 0
    const int om = swz(nr, nr * 128 + 64 + np * 4);
    *(u32*)&XMH[om] = 0; *(u32*)&XMH[om + 2] = 0;
    *(u32*)&XML[om] = 0; *(u32*)&XML[om + 2] = 0;
  }
  __syncthreads();

  for (int t = kL - 1; t >= 0; --t) {
    {  // s0: stage state(t) -> XS
      f32x4 v = *reinterpret_cast<const f32x4*>(
          state + ((size_t)(rowBase + nr) * kL + t) * 64 + np * 4);
      u16 h0, h1, h2, h3, l0, l1, l2, l3;
      split2(v[0], h0, l0); split2(v[1], h1, l1);
      split2(v[2], h2, l2); split2(v[3], h3, l3);
      const int o = swz(nr, nr * 64 + np * 4);
      *(u32*)&XSH[o] = (u32)h0 | ((u32)h1 << 16);
      *(u32*)&XSH[o + 2] = (u32)h2 | ((u32)h3 << 16);
      *(u32*)&XSL[o] = (u32)l0 | ((u32)l1 << 16);
      *(u32*)&XSL[o + 2] = (u32)l2 | ((u32)l3 << 16);
    }
    __syncthreads();
    {  // s1: U1 -> SMC raw
      MM64(OFF_U1, 64, XSH, XSL, 64, rowq);
      #pragma unroll
      for (int i = 0; i < 4; ++i)
        SMC[(rowq * 16 + g * 4 + i) * 64 + c64] = acc64[i] + ub1v;
    }
    __syncthreads();
    {  // s2: normalize + tanh -> XM[0:64]
      f32x4 v = *reinterpret_cast<const f32x4*>(SMC + nr * 64 + np * 4);
      float ss = v[0]*v[0] + v[1]*v[1] + v[2]*v[2] + v[3]*v[3];
      ss += __shfl_xor(ss, 8); ss += __shfl_xor(ss, 4);
      ss += __shfl_xor(ss, 2); ss += __shfl_xor(ss, 1);
      const float inv = 1.f / fmaxf(sqrtf(ss), 1e-12f);
      u16 h0, h1, h2, h3, l0, l1, l2, l3;
      split2(tfast(v[0] * inv), h0, l0); split2(tfast(v[1] * inv), h1, l1);
      split2(tfast(v[2] * inv), h2, l2); split2(tfast(v[3] * inv), h3, l3);
      const int o = swz(nr, nr * 128 + np * 4);
      *(u32*)&XMH[o] = (u32)h0 | ((u32)h1 << 16);
      *(u32*)&XMH[o + 2] = (u32)h2 | ((u32)h3 << 16);
      *(u32*)&XML[o] = (u32)l0 | ((u32)l1 << 16);
      *(u32*)&XML[o + 2] = (u32)l2 | ((u32)l3 << 16);
    }
    __syncthreads();
    {  // s3: U2 (K=128) -> tanh -> H2
      MM64(OFF_U2, 128, XMH, XML, 128, rowq);
      #pragma unroll
      for (int i = 0; i < 4; ++i) {
        u16 hh, ll;
        split2(tfast(acc64[i] + ub2v), hh, ll);
        const int row = rowq * 16 + g * 4 + i;
        const int o = swz(row, row * 64 + c64);
        H2H[o] = hh; H2L[o] = ll;
      }
    }
    __syncthreads();
    {  // s4: U3 -> SMC raw
      MM64(OFF_U3, 64, H2H, H2L, 64, rowq);
      #pragma unroll
      for (int i = 0; i < 4; ++i)
        SMC[(rowq * 16 + g * 4 + i) * 64 + c64] = acc64[i] + ub3v;
    }
    __syncthreads();
    {  // s5: normalize -> msg (global) ; XM[64:] = split(tanh(msg))
      f32x4 v = *reinterpret_cast<const f32x4*>(SMC + nr * 64 + np * 4);
      float ss = v[0]*v[0] + v[1]*v[1] + v[2]*v[2] + v[3]*v[3];
      ss += __shfl_xor(ss, 8); ss += __shfl_xor(ss, 4);
      ss += __shfl_xor(ss, 2); ss += __shfl_xor(ss, 1);
      const float inv = 1.f / fmaxf(sqrtf(ss), 1e-12f);
      const float m0 = v[0] * inv, m1 = v[1] * inv;
      const float m2 = v[2] * inv, m3 = v[3] * inv;
      u16* mp = msgs + ((size_t)(rowBase + nr) * kL + t) * 64 + np * 4;
      *(u32*)mp = (u32)f2bf(m0) | ((u32)f2bf(m1) << 16);
      *(u32*)(mp + 2) = (u32)f2bf(m2) | ((u32)f2bf(m3) << 16);
      u16 h0, h1, h2, h3, l0, l1, l2, l3;
      split2(tfast(m0), h0, l0); split2(tfast(m1), h1, l1);
      split2(tfast(m2), h2, l2); split2(tfast(m3), h3, l3);
      const int om = swz(nr, nr * 128 + 64 + np * 4);
      *(u32*)&XMH[om] = (u32)h0 | ((u32)h1 << 16);
      *(u32*)&XMH[om + 2] = (u32)h2 | ((u32)h3 << 16);
      *(u32*)&XML[om] = (u32)l0 | ((u32)l1 << 16);
      *(u32*)&XML[om + 2] = (u32)l2 | ((u32)l3 << 16);
    }
    __syncthreads();
  }
}

// -------- TD step t: RPB=64, 512 thr, NT=1/NM=4, fenced passes --------
__global__ __launch_bounds__(512) void td_step_kernel(
    const float* __restrict__ ab1, const float* __restrict__ ab2,
    const float* __restrict__ aW3, const float* __restrict__ ab3,
    const float* __restrict__ mb1, const float* __restrict__ mb2,
    const float* __restrict__ mb3,
    const u16* __restrict__ wsp, const u16* __restrict__ msgs,
    float* __restrict__ carry, float* __restrict__ out, int t) {
  __shared__ __align__(16) u16 lds[81920];  // 160 KB
  u16* XMH = lds;             // 64x128
  u16* XML = lds + 8192;
  u16* B1H = lds + 16384;     // 64x256
  u16* B1L = lds + 32768;
  u16* B2H = lds + 49152;     // 64x256
  u16* B2L = lds + 65536;
  float* SMC = reinterpret_cast<float*>(B1H);  // 64x64 f32, B1 dead after M2

  const int tid = threadIdx.x;
  const int wv = tid >> 6, lane = tid & 63;
  const int r15 = lane & 15, g = lane >> 4;
  const int nq = wv & 3, rowh = wv >> 2;     // M3: 4 col-tiles x 2 row-halves
  const int nr = tid >> 4, np = tid & 15;    // 32 rows x 16 lanes (x2 row passes)
  const int rowBase = blockIdx.x * 64;
  const int cA = wv * 16;                    // pass-0 col base; pass-1 = cA+128
  const int c64 = nq * 16 + r15;

  {  // p0: XM rows {nr, nr+32} = [split(tanh(msg_t)) | split(tanh(m_prev))]
    #pragma unroll
    for (int rp = 0; rp < 2; ++rp) {
      const int rr = nr + rp * 32;
      const u16* mp = msgs + ((size_t)(rowBase + rr) * kL + t) * 64 + np * 4;
      const u32 w0 = *(const u32*)mp;
      const u32 w1 = *(const u32*)(mp + 2);
      u16 h0, h1, h2, h3, l0, l1, l2, l3;
      split2(tfast(bf2f((u16)w0)), h0, l0);
      split2(tfast(bf2f((u16)(w0 >> 16))), h1, l1);
      split2(tfast(bf2f((u16)w1)), h2, l2);
      split2(tfast(bf2f((u16)(w1 >> 16))), h3, l3);
      const int o = swz(rr, rr * 128 + np * 4);
      *(u32*)&XMH[o] = (u32)h0 | ((u32)h1 << 16);
      *(u32*)&XMH[o + 2] = (u32)h2 | ((u32)h3 << 16);
      *(u32*)&XML[o] = (u32)l0 | ((u32)l1 << 16);
      *(u32*)&XML[o + 2] = (u32)l2 | ((u32)l3 << 16);

      f32x4 mprev = {0.f, 0.f, 0.f, 0.f};
      if (t > 0)
        mprev = *reinterpret_cast<const f32x4*>(
            carry + (size_t)(rowBase + rr) * 64 + np * 4);
      u16 mh0, mh1, mh2, mh3, ml0, ml1, ml2, ml3;
      split2(tfast(mprev[0]), mh0, ml0); split2(tfast(mprev[1]), mh1, ml1);
      split2(tfast(mprev[2]), mh2, ml2); split2(tfast(mprev[3]), mh3, ml3);
      const int om = swz(rr, rr * 128 + 64 + np * 4);
      *(u32*)&XMH[om] = (u32)mh0 | ((u32)mh1 << 16);
      *(u32*)&XMH[om + 2] = (u32)mh2 | ((u32)mh3 << 16);
      *(u32*)&XML[om] = (u32)ml0 | ((u32)ml1 << 16);
      *(u32*)&XML[om + 2] = (u32)ml2 | ((u32)ml3 << 16);
    }
  }
  __syncthreads();
  {  // p1: A1 -> B1 (two fenced col passes)
    TD256P(OFF_A1, ab1, XMH, XML, 128, B1H, B1L, cA);
    __builtin_amdgcn_sched_barrier(0);
    TD256P(OFF_A1, ab1, XMH, XML, 128, B1H, B1L, cA + 128);
  }
  __syncthreads();
  {  // p2: A2 -> B2
    TD256P(OFF_A2, ab2, B1H, B1L, 256, B2H, B2L, cA);
    __builtin_amdgcn_sched_barrier(0);
    TD256P(OFF_A2, ab2, B1H, B1L, 256, B2H, B2L, cA + 128);
  }
  __syncthreads();
  {  // p3: a3 (B2 -> out, rows nr & nr+32) + M1 (XM -> B1)
    {
      const f32x4 w3a = *reinterpret_cast<const f32x4*>(aW3 + np * 16);
      const f32x4 w3b = *reinterpret_cast<const f32x4*>(aW3 + np * 16 + 4);
      const f32x4 w3c = *reinterpret_cast<const f32x4*>(aW3 + np * 16 + 8);
      const f32x4 w3d = *reinterpret_cast<const f32x4*>(aW3 + np * 16 + 12);
      const float ab3v = ab3[0];
      #pragma unroll
      for (int rp = 0; rp < 2; ++rp) {
        const int rr = nr + rp * 32;
        const int o0 = swz(rr, rr * 256 + np * 16);
        const int o1 = swz(rr, rr * 256 + np * 16 + 8);
        s16x8 d0h = ldsf(B2H + o0), d1h = ldsf(B2H + o1);
        s16x8 d0l = ldsf(B2L + o0), d1l = ldsf(B2L + o1);
        float sum = 0.f;
        #pragma unroll
        for (int j = 0; j < 4; ++j) {
          sum += (bf2f((u16)d0h[j]) + bf2f((u16)d0l[j])) * w3a[j];
          sum += (bf2f((u16)d0h[4 + j]) + bf2f((u16)d0l[4 + j])) * w3b[j];
          sum += (bf2f((u16)d1h[j]) + bf2f((u16)d1l[j])) * w3c[j];
          sum += (bf2f((u16)d1h[4 + j]) + bf2f((u16)d1l[4 + j])) * w3d[j];
        }
        sum += __shfl_xor(sum, 8); sum += __shfl_xor(sum, 4);
        sum += __shfl_xor(sum, 2); sum += __shfl_xor(sum, 1);
        if (np == 0) out[(size_t)(rowBase + rr) * kL + t] = tfast(sum + ab3v);
      }
    }
    __builtin_amdgcn_sched_barrier(0);
    TD256P(OFF_M1, mb1, XMH, XML, 128, B1H, B1L, cA);
    __builtin_amdgcn_sched_barrier(0);
    TD256P(OFF_M1, mb1, XMH, XML, 128, B1H, B1L, cA + 128);
  }
  __syncthreads();
  {  // p4: M2 -> B2
    TD256P(OFF_M2, mb2, B1H, B1L, 256, B2H, B2L, cA);
    __builtin_amdgcn_sched_barrier(0);
    TD256P(OFF_M2, mb2, B1H, B1L, 256, B2H, B2L, cA + 128);
  }
  __syncthreads();
  {  // p5: M3 -> SMC raw (rows rowh*32 + {0,16}; aliases B1H, B1 dead)
    const float mb3v = mb3[c64];
    f32x4 e0 = {0.f, 0.f, 0.f, 0.f}, e1 = e0;
    const u16* Bp_ = wsp + OFF_M3;
    #pragma unroll
    for (int kt = 0; kt < 8; ++kt) {
      const u16* bp_ = Bp_ + (kt * 64 + c64) * 64 + g * 8;
      s16x8 bh = ldsf(bp_), bl = ldsf(bp_ + 32);
      const int r0_ = rowh * 32 + r15;
      const int of0_ = swz(r0_, r0_ * 256 + kt * 32 + g * 8);
      s16x8 a0h = ldsf(B2H + of0_), a0l = ldsf(B2L + of0_);
      e0 = mfma16(a0h, bh, e0);
      e0 = mfma16(a0l, bh, e0);
      e0 = mfma16(a0h, bl, e0);
      const int r1_ = rowh * 32 + 16 + r15;
      const int of1_ = swz(r1_, r1_ * 256 + kt * 32 + g * 8);
      s16x8 a1h = ldsf(B2H + of1_), a1l = ldsf(B2L + of1_);
      e1 = mfma16(a1h, bh, e1);
      e1 = mfma16(a1l, bh, e1);
      e1 = mfma16(a1h, bl, e1);
    }
    #pragma unroll
    for (int i = 0; i < 4; ++i) {
      SMC[(rowh * 32 + g * 4 + i) * 64 + c64] = e0[i] + mb3v;
      SMC[(rowh * 32 + 16 + g * 4 + i) * 64 + c64] = e1[i] + mb3v;
    }
  }
  __syncthreads();
  {  // p6: normalize rows {nr, nr+32} -> carry
    #pragma unroll
    for (int rp = 0; rp < 2; ++rp) {
      const int rr = nr + rp * 32;
      f32x4 v = *reinterpret_cast<const f32x4*>(SMC + rr * 64 + np * 4);
      float ss = v[0]*v[0] + v[1]*v[1] + v[2]*v[2] + v[3]*v[3];
      ss += __shfl_xor(ss, 8); ss += __shfl_xor(ss, 4);
      ss += __shfl_xor(ss, 2); ss += __shfl_xor(ss, 1);
      const float inv = 1.f / fmaxf(sqrtf(ss), 1e-12f);
      f32x4 m;
      m[0] = v[0] * inv; m[1] = v[1] * inv; m[2] = v[2] * inv; m[3] = v[3] * inv;
      *reinterpret_cast<f32x4*>(carry + (size_t)(rowBase + rr) * 64 + np * 4) = m;
    }
  }
}

extern "C" void kernel_launch(void* const* d_in, const int* in_sizes, int n_in,
                              void* d_out, int out_size, void* d_ws, size_t ws_size,
                              hipStream_t stream) {
  (void)in_sizes; (void)n_in; (void)out_size;
  const float* state = (const float*)d_in[0];
  const float* uW1 = (const float*)d_in[1];
  const float* ub1 = (const float*)d_in[2];
  const float* uW2 = (const float*)d_in[3];
  const float* ub2 = (const float*)d_in[4];
  const float* uW3 = (const float*)d_in[5];
  const float* ub3 = (const float*)d_in[6];
  const float* aW1 = (const float*)d_in[7];
  const float* ab1 = (const float*)d_in[8];
  const float* aW2 = (const float*)d_in[9];
  const float* ab2 = (const float*)d_in[10];
  const float* aW3 = (const float*)d_in[11];
  const float* ab3 = (const float*)d_in[12];
  const float* mW1 = (const float*)d_in[13];
  const float* mb1 = (const float*)d_in[14];
  const float* mW2 = (const float*)d_in[15];
  const float* mb2 = (const float*)d_in[16];
  const float* mW3 = (const float*)d_in[17];
  const float* mb3 = (const float*)d_in[18];
  u16* wsp = (u16*)d_ws;
  float* out = (float*)d_out;

  if (ws_size < WS_NEED) return;
  u16* msgs = wsp + MSG_OFF;
  float* carry = reinterpret_cast<float*>(wsp + CD_OFF);

  hipLaunchKernelGGL(prep_kernel, dim3(896), dim3(256), 0, stream,
                     aW1, aW2, mW1, mW2, mW3, uW1, uW2, uW3, wsp);
  hipLaunchKernelGGL(bu_all_kernel, dim3(kB / 32), dim3(512), 0, stream,
                     state, ub1, ub2, ub3, wsp, msgs);
  for (int t = 0; t < kL; ++t)
    hipLaunchKernelGGL(td_step_kernel, dim3(kB / 64), dim3(512), 0, stream,
                       ab1, ab2, aW3, ab3, mb1, mb2, mb3,
                       wsp, msgs, carry, out, t);
}